// Round 10
// baseline (1099.543 us; speedup 1.0000x reference)
//
#include <hip/hip_runtime.h>
#include <math.h>

#define EXPERTS 8
#define DEPTH 6
#define DIM 512
#define HEADS 8
#define NCLS 10
#define BATCH 128
#define PD 48
#define NTOK 65
#define NRT256 40              // max 256-row tiles
#define NRT128 80
#define NRT32 (NRT256 * 8)     // 32-row tiles (fused GEMM)
#define NROWSP (NRT256 * 256)  // 10240 gathered rows

typedef __attribute__((ext_vector_type(4))) float f32x4;
typedef __attribute__((ext_vector_type(8))) __bf16 bf16x8;
typedef unsigned short u16;

#define GLOAD_LDS16(gp, lp)                                                     \
    __builtin_amdgcn_global_load_lds(                                           \
        (const __attribute__((address_space(1))) void*)(gp),                    \
        (__attribute__((address_space(3))) void*)(lp), 16, 0, 0)

__device__ inline u16 f2bf(float f) {
    union { float f; unsigned u; } v; v.f = f;
    unsigned r = v.u + 0x7FFFu + ((v.u >> 16) & 1u);
    return (u16)(r >> 16);
}
__device__ inline float bf2f(u16 s) {
    union { unsigned u; float f; } v; v.u = ((unsigned)s) << 16;
    return v.f;
}

// ---------------------------------------------------------------------------
// Gate (exact fp32 — routing must not flip)
// ---------------------------------------------------------------------------
__global__ __launch_bounds__(256) void gate_k(const float* __restrict__ x,
                                              const float* __restrict__ gw,
                                              const float* __restrict__ gb,
                                              int* __restrict__ top1) {
    int b = blockIdx.x, tid = threadIdx.x;
    const float* xb = x + (size_t)b * 3072;
    float acc[EXPERTS];
#pragma unroll
    for (int e = 0; e < EXPERTS; ++e) acc[e] = 0.f;
    for (int i = tid; i < 3072; i += 256) {
        float xv = xb[i];
#pragma unroll
        for (int e = 0; e < EXPERTS; ++e)
            acc[e] = fmaf(xv, gw[(size_t)e * 3072 + i], acc[e]);
    }
    __shared__ float red[256];
    __shared__ float logits[EXPERTS];
    for (int e = 0; e < EXPERTS; ++e) {
        red[tid] = acc[e];
        __syncthreads();
        for (int s = 128; s > 0; s >>= 1) {
            if (tid < s) red[tid] += red[tid + s];
            __syncthreads();
        }
        if (tid == 0) logits[e] = red[0] + gb[e];
        __syncthreads();
    }
    if (tid == 0) {
        int best = 0;
        float bv = logits[0];
        for (int e = 1; e < EXPERTS; ++e)
            if (logits[e] > bv) { bv = logits[e]; best = e; }
        top1[b] = best;
    }
}

// ---------------------------------------------------------------------------
// Routing: gathered rows, experts padded to 256-row tiles.
// ---------------------------------------------------------------------------
__global__ __launch_bounds__(128) void route3_k(const int* __restrict__ top1,
                                                int* __restrict__ prow,
                                                int* __restrict__ tile_e) {
    __shared__ int t1[BATCH];
    int tid = threadIdx.x;
    t1[tid] = top1[tid];
    __syncthreads();
    if (tid != 0) return;
    int row = 0, tile = 0;
    for (int e = 0; e < EXPERTS; ++e) {
        int ne = 0;
        for (int b = 0; b < BATCH; ++b)
            if (t1[b] == e) { prow[b] = row + ne * 65; ne++; }
        if (!ne) continue;
        int nt = (ne * 65 + 255) >> 8;
        for (int tt = 0; tt < nt; ++tt) tile_e[tile++] = e;
        row += nt << 8;
    }
    for (; tile < NRT256; ++tile) tile_e[tile] = -1;
}

// ---------------------------------------------------------------------------
// Patch embed (fp32, writes gathered residual stream t, linear)
// ---------------------------------------------------------------------------
__global__ __launch_bounds__(256) void patch_k(const float* __restrict__ x,
                                               const float* __restrict__ pln1_g,
                                               const float* __restrict__ pln1_b,
                                               const float* __restrict__ patch_w,
                                               const float* __restrict__ patch_b,
                                               const float* __restrict__ pln2_g,
                                               const float* __restrict__ pln2_b,
                                               const float* __restrict__ cls_tok,
                                               const float* __restrict__ pos_emb,
                                               const int* __restrict__ top1,
                                               const int* __restrict__ prow,
                                               float* __restrict__ t) {
    int n = blockIdx.x, b = blockIdx.y, tid = threadIdx.x;
    int e = top1[b];
    float* trow = t + ((size_t)prow[b] + n) * DIM;
    const float* pe = pos_emb + ((size_t)e * NTOK + n) * DIM;

    if (n == 0) {
        for (int d = tid; d < DIM; d += 256)
            trow[d] = cls_tok[e * DIM + d] + pe[d];
        return;
    }
    int pi = n - 1, h = pi >> 3, w = pi & 7;
    __shared__ float pv[PD];
    __shared__ float red[256];
    if (tid < PD) {
        int p1 = tid / 12, rem = tid % 12, p2 = rem / 3, c = rem % 3;
        pv[tid] = x[((size_t)b * 3 + c) * 1024 + (h * 4 + p1) * 32 + (w * 4 + p2)];
    }
    __syncthreads();
    float m = 0.f, q = 0.f;
    for (int j = 0; j < PD; ++j) { float v = pv[j]; m += v; q += v * v; }
    m *= (1.f / PD);
    q = q * (1.f / PD) - m * m;
    float rs = rsqrtf(q + 1e-5f);
    __syncthreads();
    if (tid < PD)
        pv[tid] = (pv[tid] - m) * rs * pln1_g[e * PD + tid] + pln1_b[e * PD + tid];
    __syncthreads();

    float acc0 = patch_b[e * DIM + tid];
    float acc1 = patch_b[e * DIM + tid + 256];
    for (int j = 0; j < PD; ++j) {
        float v = pv[j];
        const float* wr = patch_w + ((size_t)e * PD + j) * DIM;
        acc0 = fmaf(v, wr[tid], acc0);
        acc1 = fmaf(v, wr[tid + 256], acc1);
    }
    red[tid] = acc0 + acc1;
    __syncthreads();
    for (int s = 128; s > 0; s >>= 1) {
        if (tid < s) red[tid] += red[tid + s];
        __syncthreads();
    }
    float S = red[0];
    __syncthreads();
    red[tid] = acc0 * acc0 + acc1 * acc1;
    __syncthreads();
    for (int s = 128; s > 0; s >>= 1) {
        if (tid < s) red[tid] += red[tid + s];
        __syncthreads();
    }
    float Q = red[0];
    float mean = S * (1.f / DIM);
    float var = Q * (1.f / DIM) - mean * mean;
    float rs2 = rsqrtf(var + 1e-5f);
    trow[tid]       = (acc0 - mean) * rs2 * pln2_g[e * DIM + tid]       + pln2_b[e * DIM + tid]       + pe[tid];
    trow[tid + 256] = (acc1 - mean) * rs2 * pln2_g[e * DIM + tid + 256] + pln2_b[e * DIM + tid + 256] + pe[tid + 256];
}

// ---------------------------------------------------------------------------
// LayerNorm over gathered rows (layer-0 prologue only): fp32 -> bf16 SWZ.
// ---------------------------------------------------------------------------
__global__ __launch_bounds__(256) void ln2_k(const float* __restrict__ src,
                                             u16* __restrict__ dst,
                                             const float* __restrict__ gbase,
                                             const float* __restrict__ bbase,
                                             const int* __restrict__ tile_e,
                                             int gestride) {
    int row = blockIdx.x * 4 + (threadIdx.x >> 6);
    int lane = threadIdx.x & 63;
    int e = tile_e[row >> 8];
    if (e < 0) return;
    const float* s = src + (size_t)row * 512;
    float4 a = *(const float4*)&s[lane * 4];
    float4 b = *(const float4*)&s[256 + lane * 4];
    float sum = a.x + a.y + a.z + a.w + b.x + b.y + b.z + b.w;
    float sq = a.x * a.x + a.y * a.y + a.z * a.z + a.w * a.w +
               b.x * b.x + b.y * b.y + b.z * b.z + b.w * b.w;
#pragma unroll
    for (int off = 32; off > 0; off >>= 1) {
        sum += __shfl_xor(sum, off);
        sq += __shfl_xor(sq, off);
    }
    float mean = sum * (1.f / DIM);
    float rs = rsqrtf(sq * (1.f / DIM) - mean * mean + 1e-5f);
    const float* g = gbase + (size_t)e * gestride;
    const float* bb = bbase + (size_t)e * gestride;
    float4 g0 = *(const float4*)&g[lane * 4];
    float4 g1 = *(const float4*)&g[256 + lane * 4];
    float4 b0 = *(const float4*)&bb[lane * 4];
    float4 b1 = *(const float4*)&bb[256 + lane * 4];
    int swz = (row & 7) << 3;
    u16 o[4];
    o[0] = f2bf((a.x - mean) * rs * g0.x + b0.x);
    o[1] = f2bf((a.y - mean) * rs * g0.y + b0.y);
    o[2] = f2bf((a.z - mean) * rs * g0.z + b0.z);
    o[3] = f2bf((a.w - mean) * rs * g0.w + b0.w);
    *(int2*)&dst[(size_t)row * 512 + ((lane * 4) ^ swz)] = *(int2*)o;
    o[0] = f2bf((b.x - mean) * rs * g1.x + b1.x);
    o[1] = f2bf((b.y - mean) * rs * g1.y + b1.y);
    o[2] = f2bf((b.z - mean) * rs * g1.z + b1.z);
    o[3] = f2bf((b.w - mean) * rs * g1.w + b1.w);
    *(int2*)&dst[(size_t)row * 512 + ((256 + lane * 4) ^ swz)] = *(int2*)o;
}

// ---------------------------------------------------------------------------
// Weight convert fp32 [512][N] -> bf16 [N][512] transposed + st8-swizzled.
// ---------------------------------------------------------------------------
__device__ inline void wconv_body(const float* __restrict__ s,
                                  u16* __restrict__ d, int N,
                                  int n0, int k0, int tid) {
    __shared__ float tile[32][33];
    int r = tid >> 5, c = tid & 31;
#pragma unroll
    for (int i = 0; i < 4; ++i)
        tile[r + i * 8][c] = s[(size_t)(k0 + r + i * 8) * N + n0 + c];
    __syncthreads();
#pragma unroll
    for (int i = 0; i < 4; ++i) {
        int n = n0 + r + i * 8;
        d[(size_t)n * 512 + ((k0 + c) ^ ((n & 7) << 3))] = f2bf(tile[c][r + i * 8]);
    }
}

__global__ __launch_bounds__(256) void wconv_k(const float* __restrict__ src,
                                               u16* __restrict__ dst, int N) {
    wconv_body(src + (size_t)blockIdx.z * 512 * N, dst + (size_t)blockIdx.z * 512 * N,
               N, blockIdx.x * 32, blockIdx.y * 32, threadIdx.x);
}

// one launch for the three 512-wide weight sets; grid (16,16,144)
__global__ __launch_bounds__(256) void wconv3_k(const float* __restrict__ s0,
                                                const float* __restrict__ s1,
                                                const float* __restrict__ s2,
                                                u16* __restrict__ d0,
                                                u16* __restrict__ d1,
                                                u16* __restrict__ d2) {
    int z = blockIdx.z, which = z / 48, m = z % 48;
    const float* s = (which == 0) ? s0 : (which == 1) ? s1 : s2;
    u16* d = (which == 0) ? d0 : (which == 1) ? d1 : d2;
    wconv_body(s + (size_t)m * 512 * 512, d + (size_t)m * 512 * 512,
               512, blockIdx.x * 32, blockIdx.y * 32, threadIdx.x);
}

// ---------------------------------------------------------------------------
// qkv GEMM: M=256 x N=128 tiles, 512 threads (8 waves, 4M x 2N of 64x64).
// ---------------------------------------------------------------------------
__global__ __launch_bounds__(512) void mgemm6_k(const u16* __restrict__ A,
                                                const u16* __restrict__ Wtbase,
                                                u16* __restrict__ C,
                                                const int* __restrict__ tile_e,
                                                int westride) {
    constexpr int N = 1536, CT = 12;
    int orig = blockIdx.x, nwg = NRT256 * CT;
    int q = nwg >> 3, r8 = nwg & 7;
    int xcd = orig & 7, off = orig >> 3;
    int wg = (xcd < r8 ? xcd * (q + 1) : r8 * (q + 1) + (xcd - r8) * q) + off;
    int tile = wg / CT, ct = wg - tile * CT;
    int e = tile_e[tile];
    if (e < 0) return;
    int row0 = tile * 256, c0 = ct * 128;
    const u16* Wt = Wtbase + (size_t)e * westride;

    int tid = threadIdx.x;
    int lane = tid & 63, w = tid >> 6;
    int rl = lane & 15, kg = lane >> 4;
    int wr = w >> 1, wc = w & 1;

    __shared__ __align__(16) u16 As[256 * 64];
    __shared__ __align__(16) u16 Bs[128 * 64];

    f32x4 acc[4][4];
#pragma unroll
    for (int mt = 0; mt < 4; ++mt)
#pragma unroll
        for (int nt = 0; nt < 4; ++nt) acc[mt][nt] = (f32x4){0.f, 0.f, 0.f, 0.f};

    const u16* Ag = A + (size_t)(row0 + w * 32 + (lane >> 3)) * 512 + (lane & 7) * 8;
    const u16* Bg = Wt + (size_t)(c0 + w * 16 + (lane >> 3)) * 512 + (lane & 7) * 8;
    u16* Asw = As + w * 2048;
    u16* Bsw = Bs + w * 1024;

    int blk0 = (kg ^ (rl & 7)) * 8;
    int blk1 = ((4 + kg) ^ (rl & 7)) * 8;

    for (int k0 = 0; k0 < 512; k0 += 64) {
#pragma unroll
        for (int i = 0; i < 4; ++i)
            GLOAD_LDS16(Ag + k0 + i * 8 * 512, Asw + i * 512);
#pragma unroll
        for (int i = 0; i < 2; ++i)
            GLOAD_LDS16(Bg + k0 + i * 8 * 512, Bsw + i * 512);
        __syncthreads();
#pragma unroll
        for (int ks = 0; ks < 2; ++ks) {
            int blk = ks ? blk1 : blk0;
            bf16x8 av[4], bv[4];
#pragma unroll
            for (int i = 0; i < 4; ++i) {
                av[i] = *(const bf16x8*)&As[(wr * 64 + i * 16 + rl) * 64 + blk];
                bv[i] = *(const bf16x8*)&Bs[(wc * 64 + i * 16 + rl) * 64 + blk];
            }
#pragma unroll
            for (int mt = 0; mt < 4; ++mt)
#pragma unroll
                for (int nt = 0; nt < 4; ++nt)
                    acc[mt][nt] = __builtin_amdgcn_mfma_f32_16x16x32_bf16(
                        av[mt], bv[nt], acc[mt][nt], 0, 0, 0);
        }
        __syncthreads();
    }

    int rh = lane >> 4;
#pragma unroll
    for (int mt = 0; mt < 4; ++mt)
#pragma unroll
        for (int nt = 0; nt < 4; ++nt)
#pragma unroll
            for (int rr = 0; rr < 4; ++rr) {
                size_t grow = row0 + wr * 64 + mt * 16 + rh * 4 + rr;
                int c = c0 + wc * 64 + nt * 16 + rl;
                C[grow * N + c] = f2bf(acc[mt][nt][rr]);
            }
}

// ---------------------------------------------------------------------------
// ff1 GEMM (GELU): M=128 x N=128, 4 waves. grid = NRT128 * 4.
// ---------------------------------------------------------------------------
__global__ __launch_bounds__(256) void mgemm5g_k(const u16* __restrict__ A,
                                                 const u16* __restrict__ Wtbase,
                                                 const float* __restrict__ Bbase,
                                                 u16* __restrict__ C,
                                                 const int* __restrict__ tile_e,
                                                 int westride, int bestride) {
    constexpr int CT = 4;
    int orig = blockIdx.x, nwg = NRT128 * CT;
    int q = nwg >> 3, r8 = nwg & 7;
    int xcd = orig & 7, off = orig >> 3;
    int wg = (xcd < r8 ? xcd * (q + 1) : r8 * (q + 1) + (xcd - r8) * q) + off;
    int tile = wg / CT, ct = wg - tile * CT;
    int e = tile_e[tile >> 1];
    if (e < 0) return;
    int row0 = tile * 128, c0 = ct * 128;
    const u16* Wt = Wtbase + (size_t)e * westride;

    int tid = threadIdx.x;
    int lane = tid & 63, w = tid >> 6;
    int rl = lane & 15, kg = lane >> 4;
    int wr = w >> 1, wc = w & 1;

    __shared__ __align__(16) u16 As[128 * 64];
    __shared__ __align__(16) u16 Bs[128 * 64];

    f32x4 acc[4][4];
#pragma unroll
    for (int mt = 0; mt < 4; ++mt)
#pragma unroll
        for (int nt = 0; nt < 4; ++nt) acc[mt][nt] = (f32x4){0.f, 0.f, 0.f, 0.f};

    const u16* Ag = A + (size_t)(row0 + w * 32 + (lane >> 3)) * 512 + (lane & 7) * 8;
    const u16* Bg = Wt + (size_t)(c0 + w * 32 + (lane >> 3)) * 512 + (lane & 7) * 8;
    u16* Asw = As + w * 2048;
    u16* Bsw = Bs + w * 2048;

    int blk0 = (kg ^ (rl & 7)) * 8;
    int blk1 = ((4 + kg) ^ (rl & 7)) * 8;

    for (int k0 = 0; k0 < 512; k0 += 64) {
#pragma unroll
        for (int i = 0; i < 4; ++i) {
            GLOAD_LDS16(Ag + k0 + i * 8 * 512, Asw + i * 512);
            GLOAD_LDS16(Bg + k0 + i * 8 * 512, Bsw + i * 512);
        }
        __syncthreads();
#pragma unroll
        for (int ks = 0; ks < 2; ++ks) {
            int blk = ks ? blk1 : blk0;
            bf16x8 av[4], bv[4];
#pragma unroll
            for (int i = 0; i < 4; ++i) {
                av[i] = *(const bf16x8*)&As[(wr * 64 + i * 16 + rl) * 64 + blk];
                bv[i] = *(const bf16x8*)&Bs[(wc * 64 + i * 16 + rl) * 64 + blk];
            }
#pragma unroll
            for (int mt = 0; mt < 4; ++mt)
#pragma unroll
                for (int nt = 0; nt < 4; ++nt)
                    acc[mt][nt] = __builtin_amdgcn_mfma_f32_16x16x32_bf16(
                        av[mt], bv[nt], acc[mt][nt], 0, 0, 0);
        }
        __syncthreads();
    }

    int rh = lane >> 4;
#pragma unroll
    for (int mt = 0; mt < 4; ++mt)
#pragma unroll
        for (int nt = 0; nt < 4; ++nt)
#pragma unroll
            for (int rr = 0; rr < 4; ++rr) {
                size_t grow = row0 + wr * 64 + mt * 16 + rh * 4 + rr;
                int c = c0 + wc * 64 + nt * 16 + rl;
                float vb = acc[mt][nt][rr] + Bbase[(size_t)e * bestride + c];
                float gl = vb * 0.5f * (1.f + erff(vb * 0.70710678118f));
                C[grow * 512 + (c ^ (((int)grow & 7) << 3))] = f2bf(gl);
            }
}

// ---------------------------------------------------------------------------
// FUSED residual GEMM + LayerNorm: M=32 x N=512 (full row per block).
// t' = t + A@Wt + bias  -> written to T (fp32 linear)
// LNMODE=1: dst = LN(t') (bf16, st8-swizzled).  grid = NRT32 (=320), 4 waves.
// ---------------------------------------------------------------------------
template <int LNMODE>
__global__ __launch_bounds__(256) void gemmres_k(const u16* __restrict__ A,
                                                 const u16* __restrict__ Wtbase,
                                                 const float* __restrict__ Bbase,
                                                 float* __restrict__ T,
                                                 const float* __restrict__ gbase,
                                                 const float* __restrict__ bbase2,
                                                 u16* __restrict__ dst,
                                                 const int* __restrict__ tile_e,
                                                 int westride, int bestride,
                                                 int gestride) {
    int orig = blockIdx.x;                 // nwg = NRT32 = 320, 320%8==0
    int wg = (orig & 7) * (NRT32 >> 3) + (orig >> 3);
    int e = tile_e[wg >> 3];               // 8 M32-tiles per 256-tile
    if (e < 0) return;
    int row0 = wg * 32;
    const u16* Wt = Wtbase + (size_t)e * westride;

    int tid = threadIdx.x;
    int lane = tid & 63, w = tid >> 6;
    int rl = lane & 15, kg = lane >> 4, rh = lane >> 4;

    __shared__ __align__(16) u16 As[32 * 64];     // 4 KB
    __shared__ __align__(16) u16 Bs[512 * 64];    // 64 KB
    __shared__ float redS[4][32], redQ[4][32];    // 1 KB

    f32x4 acc[2][8];
#pragma unroll
    for (int mt = 0; mt < 2; ++mt)
#pragma unroll
        for (int nt = 0; nt < 8; ++nt) acc[mt][nt] = (f32x4){0.f, 0.f, 0.f, 0.f};

    const u16* Ag = A + (size_t)(row0 + w * 8 + (lane >> 3)) * 512 + (lane & 7) * 8;
    const u16* Bg = Wt + (size_t)(w * 128 + (lane >> 3)) * 512 + (lane & 7) * 8;
    u16* Asw = As + w * 512;
    u16* Bsw = Bs + w * 8192;

    int blk0 = (kg ^ (rl & 7)) * 8;
    int blk1 = ((4 + kg) ^ (rl & 7)) * 8;

    for (int k0 = 0; k0 < 512; k0 += 64) {
        GLOAD_LDS16(Ag + k0, Asw);
#pragma unroll
        for (int i = 0; i < 16; ++i)
            GLOAD_LDS16(Bg + k0 + i * 8 * 512, Bsw + i * 512);
        __syncthreads();
#pragma unroll
        for (int ks = 0; ks < 2; ++ks) {
            int blk = ks ? blk1 : blk0;
            bf16x8 av[2], bv[8];
#pragma unroll
            for (int i = 0; i < 2; ++i)
                av[i] = *(const bf16x8*)&As[(i * 16 + rl) * 64 + blk];
#pragma unroll
            for (int i = 0; i < 8; ++i)
                bv[i] = *(const bf16x8*)&Bs[(w * 128 + i * 16 + rl) * 64 + blk];
#pragma unroll
            for (int mt = 0; mt < 2; ++mt)
#pragma unroll
                for (int nt = 0; nt < 8; ++nt)
                    acc[mt][nt] = __builtin_amdgcn_mfma_f32_16x16x32_bf16(
                        av[mt], bv[nt], acc[mt][nt], 0, 0, 0);
        }
        __syncthreads();
    }

    // Epilogue: tv = t + acc + bias; row stats; write t' and LN(t').
    float bias_nt[8];
#pragma unroll
    for (int nt = 0; nt < 8; ++nt)
        bias_nt[nt] = Bbase[(size_t)e * bestride + w * 128 + nt * 16 + rl];

#pragma unroll
    for (int mt = 0; mt < 2; ++mt)
#pragma unroll
        for (int rr = 0; rr < 4; ++rr) {
            int rowl = mt * 16 + rh * 4 + rr;
            size_t grow = row0 + rowl;
            float s = 0.f, q = 0.f;
#pragma unroll
            for (int nt = 0; nt < 8; ++nt) {
                int c = w * 128 + nt * 16 + rl;
                float tv = T[grow * 512 + c] + acc[mt][nt][rr] + bias_nt[nt];
                acc[mt][nt][rr] = tv;
                s += tv;
                q += tv * tv;
            }
            s += __shfl_xor(s, 1); q += __shfl_xor(q, 1);
            s += __shfl_xor(s, 2); q += __shfl_xor(q, 2);
            s += __shfl_xor(s, 4); q += __shfl_xor(q, 4);
            s += __shfl_xor(s, 8); q += __shfl_xor(q, 8);
            if (rl == 0) { redS[w][rowl] = s; redQ[w][rowl] = q; }
        }
    __syncthreads();

#pragma unroll
    for (int mt = 0; mt < 2; ++mt)
#pragma unroll
        for (int rr = 0; rr < 4; ++rr) {
            int rowl = mt * 16 + rh * 4 + rr;
            size_t grow = row0 + rowl;
            float S = redS[0][rowl] + redS[1][rowl] + redS[2][rowl] + redS[3][rowl];
            float Q = redQ[0][rowl] + redQ[1][rowl] + redQ[2][rowl] + redQ[3][rowl];
            float mean = S * (1.f / DIM);
            float rs = rsqrtf(Q * (1.f / DIM) - mean * mean + 1e-5f);
            int swz = ((int)grow & 7) << 3;
#pragma unroll
            for (int nt = 0; nt < 8; ++nt) {
                int c = w * 128 + nt * 16 + rl;
                float tv = acc[mt][nt][rr];
                T[grow * 512 + c] = tv;
                if (LNMODE) {
                    float g = gbase[(size_t)e * gestride + c];
                    float b2 = bbase2[(size_t)e * gestride + c];
                    dst[grow * 512 + (c ^ swz)] = f2bf((tv - mean) * rs * g + b2);
                }
            }
        }
}

// ---------------------------------------------------------------------------
// MFMA attention: block per (b,h), 5 waves (320 thr), wave w owns m-tile w.
// ---------------------------------------------------------------------------
#define ATT_LDS (23040 / 2 + 8320 / 2 + 12288 / 2)
__global__ __launch_bounds__(320) void attn3_k(const u16* __restrict__ qkv,
                                               u16* __restrict__ o,
                                               const int* __restrict__ prow) {
    int h = blockIdx.x, b = blockIdx.y, tid = threadIdx.x;
    int pr = prow[b];
    __shared__ __align__(16) u16 smem[ATT_LDS];
    u16* Qs = smem;                    // [80][72]
    u16* Ks = smem + 80 * 72;          // [80][72]
    u16* Ps = smem;                    // [80][96]
    u16* Vs = smem + 2 * 80 * 72;      // [65][64]
    u16* Vt = Vs + 65 * 64;            // [64][96]

    const u16* base = qkv + (size_t)pr * 1536 + h * 64;

    for (int idx = tid; idx < 640; idx += 320) {
        int r = idx >> 3, q = idx & 7;
        int4 vq = {0, 0, 0, 0}, vk = {0, 0, 0, 0};
        if (r < NTOK) {
            vq = *(const int4*)&base[(size_t)r * 1536 + q * 8];
            vk = *(const int4*)&base[(size_t)r * 1536 + 512 + q * 8];
        }
        *(int4*)&Qs[r * 72 + q * 8] = vq;
        *(int4*)&Ks[r * 72 + q * 8] = vk;
    }
    for (int idx = tid; idx < 520; idx += 320) {
        int r = idx >> 3, q = idx & 7;
        *(int4*)&Vs[r * 64 + q * 8] = *(const int4*)&base[(size_t)r * 1536 + 1024 + q * 8];
    }
    __syncthreads();

    int lane = tid & 63, mt = tid >> 6;
    int rl = lane & 15, kg = lane >> 4, g = lane >> 4;

    f32x4 acc[5];
#pragma unroll
    for (int nt = 0; nt < 5; ++nt) acc[nt] = (f32x4){0.f, 0.f, 0.f, 0.f};

    {
        bf16x8 av0 = *(const bf16x8*)&Qs[(mt * 16 + rl) * 72 + kg * 8];
        bf16x8 av1 = *(const bf16x8*)&Qs[(mt * 16 + rl) * 72 + 32 + kg * 8];
#pragma unroll
        for (int nt = 0; nt < 5; ++nt) {
            bf16x8 bv0 = *(const bf16x8*)&Ks[(nt * 16 + rl) * 72 + kg * 8];
            bf16x8 bv1 = *(const bf16x8*)&Ks[(nt * 16 + rl) * 72 + 32 + kg * 8];
            acc[nt] = __builtin_amdgcn_mfma_f32_16x16x32_bf16(av0, bv0, acc[nt], 0, 0, 0);
            acc[nt] = __builtin_amdgcn_mfma_f32_16x16x32_bf16(av1, bv1, acc[nt], 0, 0, 0);
        }
    }

    for (int idx = tid; idx < 768; idx += 320) {
        int d = idx & 63, kq = idx >> 6;
        u16 tmp[8];
#pragma unroll
        for (int j = 0; j < 8; ++j) {
            int k = kq * 8 + j;
            tmp[j] = (k < NTOK) ? Vs[k * 64 + d] : (u16)0;
        }
        *(int4*)&Vt[d * 96 + kq * 8] = *(int4*)tmp;
    }

#pragma unroll
    for (int r = 0; r < 4; ++r) {
        float m = -3.0e38f;
#pragma unroll
        for (int nt = 0; nt < 5; ++nt) {
            float s = acc[nt][r] * 0.125f;
            if (nt * 16 + rl >= NTOK) s = -3.0e38f;
            acc[nt][r] = s;
            m = fmaxf(m, s);
        }
        m = fmaxf(m, __shfl_xor(m, 1));
        m = fmaxf(m, __shfl_xor(m, 2));
        m = fmaxf(m, __shfl_xor(m, 4));
        m = fmaxf(m, __shfl_xor(m, 8));
        float sum = 0.f;
#pragma unroll
        for (int nt = 0; nt < 5; ++nt) {
            float p = expf(acc[nt][r] - m);
            acc[nt][r] = p;
            sum += p;
        }
        sum += __shfl_xor(sum, 1);
        sum += __shfl_xor(sum, 2);
        sum += __shfl_xor(sum, 4);
        sum += __shfl_xor(sum, 8);
        float inv = 1.f / sum;
#pragma unroll
        for (int nt = 0; nt < 5; ++nt) acc[nt][r] *= inv;
    }
    __syncthreads();

#pragma unroll
    for (int nt = 0; nt < 5; ++nt)
#pragma unroll
        for (int r = 0; r < 4; ++r)
            Ps[(mt * 16 + g * 4 + r) * 96 + nt * 16 + rl] = f2bf(acc[nt][r]);
    for (int idx = tid; idx < 160; idx += 320) {
        int r = idx >> 1, hf = idx & 1;
        *(int4*)&Ps[r * 96 + 80 + hf * 8] = (int4){0, 0, 0, 0};
    }
    __syncthreads();

#pragma unroll
    for (int dt = 0; dt < 4; ++dt) {
        f32x4 oa = {0.f, 0.f, 0.f, 0.f};
#pragma unroll
        for (int s2 = 0; s2 < 3; ++s2) {
            bf16x8 av = *(const bf16x8*)&Ps[(mt * 16 + rl) * 96 + s2 * 32 + kg * 8];
            bf16x8 bv = *(const bf16x8*)&Vt[(dt * 16 + rl) * 96 + s2 * 32 + kg * 8];
            oa = __builtin_amdgcn_mfma_f32_16x16x32_bf16(av, bv, oa, 0, 0, 0);
        }
#pragma unroll
        for (int r = 0; r < 4; ++r) {
            int row = mt * 16 + g * 4 + r;
            if (row < NTOK) {
                int grow = pr + row;
                int c = h * 64 + dt * 16 + rl;
                o[(size_t)grow * DIM + (c ^ ((grow & 7) << 3))] = f2bf(oa[r]);
            }
        }
    }
}

// ---------------------------------------------------------------------------
// Final LN (token 0) + head (fp32)
// ---------------------------------------------------------------------------
__global__ __launch_bounds__(64) void final_k(const float* __restrict__ t,
                                              const float* __restrict__ fg,
                                              const float* __restrict__ fb,
                                              const float* __restrict__ hw,
                                              const float* __restrict__ hb,
                                              const int* __restrict__ top1,
                                              const int* __restrict__ prow,
                                              float* __restrict__ out) {
    int b = blockIdx.x, lane = threadIdx.x;
    int e = top1[b];
    const float* row = t + (size_t)prow[b] * DIM;
    float v[8], s = 0.f, q = 0.f;
#pragma unroll
    for (int ii = 0; ii < 8; ++ii) {
        v[ii] = row[ii * 64 + lane];
        s += v[ii];
        q += v[ii] * v[ii];
    }
    for (int off = 32; off > 0; off >>= 1) {
        s += __shfl_xor(s, off);
        q += __shfl_xor(q, off);
    }
    float mean = s * (1.f / DIM);
    float var = q * (1.f / DIM) - mean * mean;
    float rs = rsqrtf(var + 1e-5f);
    float nv[8];
#pragma unroll
    for (int ii = 0; ii < 8; ++ii) {
        int d = ii * 64 + lane;
        nv[ii] = (v[ii] - mean) * rs * fg[e * DIM + d] + fb[e * DIM + d];
    }
    for (int c = 0; c < NCLS; ++c) {
        float p = 0.f;
#pragma unroll
        for (int ii = 0; ii < 8; ++ii) {
            int d = ii * 64 + lane;
            p = fmaf(nv[ii], hw[(size_t)e * DIM * NCLS + d * NCLS + c], p);
        }
        for (int off = 32; off > 0; off >>= 1) p += __shfl_xor(p, off);
        if (lane == 0) out[b * NCLS + c] = p + hb[e * NCLS + c];
    }
}

// ---------------------------------------------------------------------------
extern "C" void kernel_launch(void* const* d_in, const int* in_sizes, int n_in,
                              void* d_out, int out_size, void* d_ws, size_t ws_size,
                              hipStream_t stream) {
    const float* x       = (const float*)d_in[0];
    const float* gate_w  = (const float*)d_in[1];
    const float* gate_b  = (const float*)d_in[2];
    const float* pln1_g  = (const float*)d_in[3];
    const float* pln1_b  = (const float*)d_in[4];
    const float* patch_w = (const float*)d_in[5];
    const float* patch_b = (const float*)d_in[6];
    const float* pln2_g  = (const float*)d_in[7];
    const float* pln2_b  = (const float*)d_in[8];
    const float* cls_tok = (const float*)d_in[9];
    const float* pos_emb = (const float*)d_in[10];
    const float* aln_g   = (const float*)d_in[11];
    const float* aln_b   = (const float*)d_in[12];
    const float* qkv_w   = (const float*)d_in[13];
    const float* out_w   = (const float*)d_in[14];
    const float* out_b   = (const float*)d_in[15];
    const float* fln_g   = (const float*)d_in[16];
    const float* fln_b   = (const float*)d_in[17];
    const float* ff1_w   = (const float*)d_in[18];
    const float* ff1_b   = (const float*)d_in[19];
    const float* ff2_w   = (const float*)d_in[20];
    const float* ff2_b   = (const float*)d_in[21];
    const float* final_g = (const float*)d_in[22];
    const float* final_b = (const float*)d_in[23];
    const float* head_w  = (const float*)d_in[24];
    const float* head_b  = (const float*)d_in[25];
    float* out = (float*)d_out;

    // Workspace (~260 MB of ~600 MB)
    int* top1   = (int*)d_ws;                                // 128
    int* prow   = top1 + 128;                                // 128
    int* tile_e = prow + 128;                                // 40 (pad)
    float* t  = (float*)((char*)d_ws + 4096);                // fp32 [NROWSP][512] linear
    u16* aln  = (u16*)(t + (size_t)NROWSP * DIM);            // bf16 [NROWSP][512] SWZ
    u16* fln  = aln + (size_t)NROWSP * DIM;                  // bf16 [NROWSP][512] SWZ
    u16* qb16 = fln + (size_t)NROWSP * DIM;                  // bf16 [NROWSP][1536] linear
    u16* ao16 = qb16 + (size_t)NROWSP * 1536;                // bf16 [NROWSP][512] SWZ
    u16* h16  = ao16 + (size_t)NROWSP * DIM;                 // bf16 [NROWSP][512] SWZ
    u16* wq_t = h16 + (size_t)NROWSP * DIM;                  // bf16 [48][1536][512] SWZ
    u16* wo_t = wq_t + (size_t)48 * 1536 * 512;              // bf16 [48][512][512] SWZ
    u16* w1_t = wo_t + (size_t)48 * 512 * 512;
    u16* w2_t = w1_t + (size_t)48 * 512 * 512;

    gate_k<<<BATCH, 256, 0, stream>>>(x, gate_w, gate_b, top1);
    route3_k<<<1, 128, 0, stream>>>(top1, prow, tile_e);
    patch_k<<<dim3(NTOK, BATCH), 256, 0, stream>>>(x, pln1_g, pln1_b, patch_w, patch_b,
                                                   pln2_g, pln2_b, cls_tok, pos_emb,
                                                   top1, prow, t);
    wconv_k<<<dim3(48, 16, 48), 256, 0, stream>>>(qkv_w, wq_t, 1536);
    wconv3_k<<<dim3(16, 16, 144), 256, 0, stream>>>(out_w, ff1_w, ff2_w, wo_t, w1_t, w2_t);

    // layer-0 attn LN
    ln2_k<<<NROWSP / 4, 256, 0, stream>>>(t, aln, aln_g, aln_b, tile_e, DEPTH * DIM);

    for (int l = 0; l < DEPTH; ++l) {
        mgemm6_k<<<NRT256 * 12, 512, 0, stream>>>(
            aln, wq_t + (size_t)l * 1536 * 512, qb16, tile_e, DEPTH * 512 * 1536);
        attn3_k<<<dim3(HEADS, BATCH), 320, 0, stream>>>(qb16, ao16, prow);
        // out-proj + residual + fLN (writes t and fln)
        gemmres_k<1><<<NRT32, 256, 0, stream>>>(
            ao16, wo_t + (size_t)l * 512 * 512, out_b + l * DIM, t,
            fln_g + l * DIM, fln_b + l * DIM, fln, tile_e,
            DEPTH * 512 * 512, DEPTH * DIM, DEPTH * DIM);
        // ff1 + GELU
        mgemm5g_k<<<NRT128 * 4, 256, 0, stream>>>(
            fln, w1_t + (size_t)l * 512 * 512, ff1_b + l * DIM, h16, tile_e,
            DEPTH * 512 * 512, DEPTH * DIM);
        // ff2 + residual + next-layer attn LN (writes t and aln)
        if (l < DEPTH - 1)
            gemmres_k<1><<<NRT32, 256, 0, stream>>>(
                h16, w2_t + (size_t)l * 512 * 512, ff2_b + l * DIM, t,
                aln_g + (l + 1) * DIM, aln_b + (l + 1) * DIM, aln, tile_e,
                DEPTH * 512 * 512, DEPTH * DIM, DEPTH * DIM);
        else
            gemmres_k<0><<<NRT32, 256, 0, stream>>>(
                h16, w2_t + (size_t)l * 512 * 512, ff2_b + l * DIM, t,
                aln_g, aln_b, aln, tile_e,
                DEPTH * 512 * 512, DEPTH * DIM, DEPTH * DIM);
    }
    final_k<<<BATCH, 64, 0, stream>>>(t, final_g, final_b, head_w, head_b, top1, prow, out);
}

// Round 11
// 972.472 us; speedup vs baseline: 1.1307x; 1.1307x over previous
//
#include <hip/hip_runtime.h>
#include <math.h>

#define EXPERTS 8
#define DEPTH 6
#define DIM 512
#define HEADS 8
#define NCLS 10
#define BATCH 128
#define PD 48
#define NTOK 65
#define NRT256 40              // max 256-row tiles
#define NRT128 80
#define NROWSP (NRT256 * 256)  // 10240 gathered rows

typedef __attribute__((ext_vector_type(4))) float f32x4;
typedef __attribute__((ext_vector_type(8))) __bf16 bf16x8;
typedef unsigned short u16;

#define GLOAD_LDS16(gp, lp)                                                     \
    __builtin_amdgcn_global_load_lds(                                           \
        (const __attribute__((address_space(1))) void*)(gp),                    \
        (__attribute__((address_space(3))) void*)(lp), 16, 0, 0)

__device__ inline u16 f2bf(float f) {
    union { float f; unsigned u; } v; v.f = f;
    unsigned r = v.u + 0x7FFFu + ((v.u >> 16) & 1u);
    return (u16)(r >> 16);
}

// ---------------------------------------------------------------------------
// Gate (exact fp32 — routing must not flip)
// ---------------------------------------------------------------------------
__global__ __launch_bounds__(256) void gate_k(const float* __restrict__ x,
                                              const float* __restrict__ gw,
                                              const float* __restrict__ gb,
                                              int* __restrict__ top1) {
    int b = blockIdx.x, tid = threadIdx.x;
    const float* xb = x + (size_t)b * 3072;
    float acc[EXPERTS];
#pragma unroll
    for (int e = 0; e < EXPERTS; ++e) acc[e] = 0.f;
    for (int i = tid; i < 3072; i += 256) {
        float xv = xb[i];
#pragma unroll
        for (int e = 0; e < EXPERTS; ++e)
            acc[e] = fmaf(xv, gw[(size_t)e * 3072 + i], acc[e]);
    }
    __shared__ float red[256];
    __shared__ float logits[EXPERTS];
    for (int e = 0; e < EXPERTS; ++e) {
        red[tid] = acc[e];
        __syncthreads();
        for (int s = 128; s > 0; s >>= 1) {
            if (tid < s) red[tid] += red[tid + s];
            __syncthreads();
        }
        if (tid == 0) logits[e] = red[0] + gb[e];
        __syncthreads();
    }
    if (tid == 0) {
        int best = 0;
        float bv = logits[0];
        for (int e = 1; e < EXPERTS; ++e)
            if (logits[e] > bv) { bv = logits[e]; best = e; }
        top1[b] = best;
    }
}

// ---------------------------------------------------------------------------
// Routing: gathered rows, experts padded to 256-row tiles.
// ---------------------------------------------------------------------------
__global__ __launch_bounds__(128) void route3_k(const int* __restrict__ top1,
                                                int* __restrict__ prow,
                                                int* __restrict__ tile_e) {
    __shared__ int t1[BATCH];
    int tid = threadIdx.x;
    t1[tid] = top1[tid];
    __syncthreads();
    if (tid != 0) return;
    int row = 0, tile = 0;
    for (int e = 0; e < EXPERTS; ++e) {
        int ne = 0;
        for (int b = 0; b < BATCH; ++b)
            if (t1[b] == e) { prow[b] = row + ne * 65; ne++; }
        if (!ne) continue;
        int nt = (ne * 65 + 255) >> 8;
        for (int tt = 0; tt < nt; ++tt) tile_e[tile++] = e;
        row += nt << 8;
    }
    for (; tile < NRT256; ++tile) tile_e[tile] = -1;
}

// ---------------------------------------------------------------------------
// Patch embed (fp32, writes gathered residual stream t, linear)
// ---------------------------------------------------------------------------
__global__ __launch_bounds__(256) void patch_k(const float* __restrict__ x,
                                               const float* __restrict__ pln1_g,
                                               const float* __restrict__ pln1_b,
                                               const float* __restrict__ patch_w,
                                               const float* __restrict__ patch_b,
                                               const float* __restrict__ pln2_g,
                                               const float* __restrict__ pln2_b,
                                               const float* __restrict__ cls_tok,
                                               const float* __restrict__ pos_emb,
                                               const int* __restrict__ top1,
                                               const int* __restrict__ prow,
                                               float* __restrict__ t) {
    int n = blockIdx.x, b = blockIdx.y, tid = threadIdx.x;
    int e = top1[b];
    float* trow = t + ((size_t)prow[b] + n) * DIM;
    const float* pe = pos_emb + ((size_t)e * NTOK + n) * DIM;

    if (n == 0) {
        for (int d = tid; d < DIM; d += 256)
            trow[d] = cls_tok[e * DIM + d] + pe[d];
        return;
    }
    int pi = n - 1, h = pi >> 3, w = pi & 7;
    __shared__ float pv[PD];
    __shared__ float red[256];
    if (tid < PD) {
        int p1 = tid / 12, rem = tid % 12, p2 = rem / 3, c = rem % 3;
        pv[tid] = x[((size_t)b * 3 + c) * 1024 + (h * 4 + p1) * 32 + (w * 4 + p2)];
    }
    __syncthreads();
    float m = 0.f, q = 0.f;
    for (int j = 0; j < PD; ++j) { float v = pv[j]; m += v; q += v * v; }
    m *= (1.f / PD);
    q = q * (1.f / PD) - m * m;
    float rs = rsqrtf(q + 1e-5f);
    __syncthreads();
    if (tid < PD)
        pv[tid] = (pv[tid] - m) * rs * pln1_g[e * PD + tid] + pln1_b[e * PD + tid];
    __syncthreads();

    float acc0 = patch_b[e * DIM + tid];
    float acc1 = patch_b[e * DIM + tid + 256];
    for (int j = 0; j < PD; ++j) {
        float v = pv[j];
        const float* wr = patch_w + ((size_t)e * PD + j) * DIM;
        acc0 = fmaf(v, wr[tid], acc0);
        acc1 = fmaf(v, wr[tid + 256], acc1);
    }
    red[tid] = acc0 + acc1;
    __syncthreads();
    for (int s = 128; s > 0; s >>= 1) {
        if (tid < s) red[tid] += red[tid + s];
        __syncthreads();
    }
    float S = red[0];
    __syncthreads();
    red[tid] = acc0 * acc0 + acc1 * acc1;
    __syncthreads();
    for (int s = 128; s > 0; s >>= 1) {
        if (tid < s) red[tid] += red[tid + s];
        __syncthreads();
    }
    float Q = red[0];
    float mean = S * (1.f / DIM);
    float var = Q * (1.f / DIM) - mean * mean;
    float rs2 = rsqrtf(var + 1e-5f);
    trow[tid]       = (acc0 - mean) * rs2 * pln2_g[e * DIM + tid]       + pln2_b[e * DIM + tid]       + pe[tid];
    trow[tid + 256] = (acc1 - mean) * rs2 * pln2_g[e * DIM + tid + 256] + pln2_b[e * DIM + tid + 256] + pe[tid + 256];
}

// ---------------------------------------------------------------------------
// LayerNorm over gathered rows: fp32 t (linear) -> bf16 dst (st8-SWIZZLED).
// ---------------------------------------------------------------------------
__global__ __launch_bounds__(256) void ln2_k(const float* __restrict__ src,
                                             u16* __restrict__ dst,
                                             const float* __restrict__ gbase,
                                             const float* __restrict__ bbase,
                                             const int* __restrict__ tile_e,
                                             int gestride) {
    int row = blockIdx.x * 4 + (threadIdx.x >> 6);
    int lane = threadIdx.x & 63;
    int e = tile_e[row >> 8];
    if (e < 0) return;
    const float* s = src + (size_t)row * 512;
    float4 a = *(const float4*)&s[lane * 4];
    float4 b = *(const float4*)&s[256 + lane * 4];
    float sum = a.x + a.y + a.z + a.w + b.x + b.y + b.z + b.w;
    float sq = a.x * a.x + a.y * a.y + a.z * a.z + a.w * a.w +
               b.x * b.x + b.y * b.y + b.z * b.z + b.w * b.w;
#pragma unroll
    for (int off = 32; off > 0; off >>= 1) {
        sum += __shfl_xor(sum, off);
        sq += __shfl_xor(sq, off);
    }
    float mean = sum * (1.f / DIM);
    float rs = rsqrtf(sq * (1.f / DIM) - mean * mean + 1e-5f);
    const float* g = gbase + (size_t)e * gestride;
    const float* bb = bbase + (size_t)e * gestride;
    float4 g0 = *(const float4*)&g[lane * 4];
    float4 g1 = *(const float4*)&g[256 + lane * 4];
    float4 b0 = *(const float4*)&bb[lane * 4];
    float4 b1 = *(const float4*)&bb[256 + lane * 4];
    int swz = (row & 7) << 3;
    u16 o[4];
    o[0] = f2bf((a.x - mean) * rs * g0.x + b0.x);
    o[1] = f2bf((a.y - mean) * rs * g0.y + b0.y);
    o[2] = f2bf((a.z - mean) * rs * g0.z + b0.z);
    o[3] = f2bf((a.w - mean) * rs * g0.w + b0.w);
    *(int2*)&dst[(size_t)row * 512 + ((lane * 4) ^ swz)] = *(int2*)o;
    o[0] = f2bf((b.x - mean) * rs * g1.x + b1.x);
    o[1] = f2bf((b.y - mean) * rs * g1.y + b1.y);
    o[2] = f2bf((b.z - mean) * rs * g1.z + b1.z);
    o[3] = f2bf((b.w - mean) * rs * g1.w + b1.w);
    *(int2*)&dst[(size_t)row * 512 + ((256 + lane * 4) ^ swz)] = *(int2*)o;
}

// ---------------------------------------------------------------------------
// B-staging from fp32 weights [512][N] (k-major) directly into st8-swizzled
// bf16 LDS [128 n][64 k]. Thread covers a 4k x 4n block.
//   write: Bs[n*64 + ((kk&~7) ^ ((n&7)<<3)) + (kk&7)] — matches frag reads.
// ---------------------------------------------------------------------------
template <int NSTRIDE>
__device__ inline void stage_b_fp32(const float* __restrict__ W, int k0, int c0,
                                    u16* __restrict__ Bs, int nb, int kq) {
    float4 wv[4];
#pragma unroll
    for (int j = 0; j < 4; ++j)
        wv[j] = *(const float4*)&W[(size_t)(k0 + kq * 4 + j) * NSTRIDE + c0 + nb * 4];
    int kk = kq * 4;
    int kbase = (kk & ~7), klo = kk & 7;
#pragma unroll
    for (int i = 0; i < 4; ++i) {
        int n = nb * 4 + i;
        u16 t4[4];
        t4[0] = f2bf(((const float*)&wv[0])[i]);
        t4[1] = f2bf(((const float*)&wv[1])[i]);
        t4[2] = f2bf(((const float*)&wv[2])[i]);
        t4[3] = f2bf(((const float*)&wv[3])[i]);
        *(int2*)&Bs[n * 64 + (kbase ^ ((n & 7) << 3)) + klo] = *(int2*)t4;
    }
}

// ---------------------------------------------------------------------------
// qkv GEMM: M=256 x N=128 tiles, 512 threads (8 waves, 4M x 2N of 64x64).
// A: global_load_lds from pre-swizzled aln. B: fp32 direct reg-staging.
// ---------------------------------------------------------------------------
__global__ __launch_bounds__(512) void mgemm6_k(const u16* __restrict__ A,
                                                const float* __restrict__ Wbase,
                                                u16* __restrict__ C,
                                                const int* __restrict__ tile_e,
                                                int westride) {
    constexpr int N = 1536, CT = 12;
    int orig = blockIdx.x, nwg = NRT256 * CT;
    int q = nwg >> 3, r8 = nwg & 7;
    int xcd = orig & 7, off = orig >> 3;
    int wg = (xcd < r8 ? xcd * (q + 1) : r8 * (q + 1) + (xcd - r8) * q) + off;
    int tile = wg / CT, ct = wg - tile * CT;
    int e = tile_e[tile];
    if (e < 0) return;
    int row0 = tile * 256, c0 = ct * 128;
    const float* W = Wbase + (size_t)e * westride;

    int tid = threadIdx.x;
    int lane = tid & 63, w = tid >> 6;
    int rl = lane & 15, kg = lane >> 4;
    int wr = w >> 1, wc = w & 1;

    __shared__ __align__(16) u16 As[256 * 64];
    __shared__ __align__(16) u16 Bs[128 * 64];

    f32x4 acc[4][4];
#pragma unroll
    for (int mt = 0; mt < 4; ++mt)
#pragma unroll
        for (int nt = 0; nt < 4; ++nt) acc[mt][nt] = (f32x4){0.f, 0.f, 0.f, 0.f};

    const u16* Ag = A + (size_t)(row0 + w * 32 + (lane >> 3)) * 512 + (lane & 7) * 8;
    u16* Asw = As + w * 2048;
    int nb = tid & 31, kq = tid >> 5;   // 32 n-quads x 16 k-quads

    int blk0 = (kg ^ (rl & 7)) * 8;
    int blk1 = ((4 + kg) ^ (rl & 7)) * 8;

    for (int k0 = 0; k0 < 512; k0 += 64) {
#pragma unroll
        for (int i = 0; i < 4; ++i)
            GLOAD_LDS16(Ag + k0 + i * 8 * 512, Asw + i * 512);
        stage_b_fp32<1536>(W, k0, c0, Bs, nb, kq);
        __syncthreads();
#pragma unroll
        for (int ks = 0; ks < 2; ++ks) {
            int blk = ks ? blk1 : blk0;
            bf16x8 av[4], bv[4];
#pragma unroll
            for (int i = 0; i < 4; ++i) {
                av[i] = *(const bf16x8*)&As[(wr * 64 + i * 16 + rl) * 64 + blk];
                bv[i] = *(const bf16x8*)&Bs[(wc * 64 + i * 16 + rl) * 64 + blk];
            }
#pragma unroll
            for (int mt = 0; mt < 4; ++mt)
#pragma unroll
                for (int nt = 0; nt < 4; ++nt)
                    acc[mt][nt] = __builtin_amdgcn_mfma_f32_16x16x32_bf16(
                        av[mt], bv[nt], acc[mt][nt], 0, 0, 0);
        }
        __syncthreads();
    }

    int rh = lane >> 4;
#pragma unroll
    for (int mt = 0; mt < 4; ++mt)
#pragma unroll
        for (int nt = 0; nt < 4; ++nt)
#pragma unroll
            for (int rr = 0; rr < 4; ++rr) {
                size_t grow = row0 + wr * 64 + mt * 16 + rh * 4 + rr;
                int c = c0 + wc * 64 + nt * 16 + rl;
                C[grow * N + c] = f2bf(acc[mt][nt][rr]);
            }
}

// ---------------------------------------------------------------------------
// 512-wide GEMM: M=128 x N=128, 4 waves (2x2 of 64x64). grid = NRT128 * 4.
// B staged directly from fp32 weights. OP: 1 = fp32 t += acc + bias;
// 2 = bias + GELU -> bf16 SWIZZLED.
// ---------------------------------------------------------------------------
template <int OP>
__global__ __launch_bounds__(256) void mgemm5_k(const u16* __restrict__ A,
                                                const float* __restrict__ Wbase,
                                                const float* __restrict__ Bbase,
                                                void* __restrict__ Cptr,
                                                const int* __restrict__ tile_e,
                                                int westride, int bestride) {
    constexpr int CT = 4;
    int orig = blockIdx.x, nwg = NRT128 * CT;
    int q = nwg >> 3, r8 = nwg & 7;
    int xcd = orig & 7, off = orig >> 3;
    int wg = (xcd < r8 ? xcd * (q + 1) : r8 * (q + 1) + (xcd - r8) * q) + off;
    int tile = wg / CT, ct = wg - tile * CT;
    int e = tile_e[tile >> 1];
    if (e < 0) return;
    int row0 = tile * 128, c0 = ct * 128;
    const float* W = Wbase + (size_t)e * westride;

    int tid = threadIdx.x;
    int lane = tid & 63, w = tid >> 6;
    int rl = lane & 15, kg = lane >> 4;
    int wr = w >> 1, wc = w & 1;

    __shared__ __align__(16) u16 As[128 * 64];
    __shared__ __align__(16) u16 Bs[128 * 64];

    f32x4 acc[4][4];
#pragma unroll
    for (int mt = 0; mt < 4; ++mt)
#pragma unroll
        for (int nt = 0; nt < 4; ++nt) acc[mt][nt] = (f32x4){0.f, 0.f, 0.f, 0.f};

    const u16* Ag = A + (size_t)(row0 + w * 32 + (lane >> 3)) * 512 + (lane & 7) * 8;
    u16* Asw = As + w * 2048;
    int nb = tid & 31, kb = tid >> 5;   // 32 n-quads x 8 k-quads (x2 halves)

    int blk0 = (kg ^ (rl & 7)) * 8;
    int blk1 = ((4 + kg) ^ (rl & 7)) * 8;

    for (int k0 = 0; k0 < 512; k0 += 64) {
#pragma unroll
        for (int i = 0; i < 4; ++i)
            GLOAD_LDS16(Ag + k0 + i * 8 * 512, Asw + i * 512);
#pragma unroll
        for (int h = 0; h < 2; ++h)
            stage_b_fp32<512>(W, k0, c0, Bs, nb, h * 8 + kb);
        __syncthreads();
#pragma unroll
        for (int ks = 0; ks < 2; ++ks) {
            int blk = ks ? blk1 : blk0;
            bf16x8 av[4], bv[4];
#pragma unroll
            for (int i = 0; i < 4; ++i) {
                av[i] = *(const bf16x8*)&As[(wr * 64 + i * 16 + rl) * 64 + blk];
                bv[i] = *(const bf16x8*)&Bs[(wc * 64 + i * 16 + rl) * 64 + blk];
            }
#pragma unroll
            for (int mt = 0; mt < 4; ++mt)
#pragma unroll
                for (int nt = 0; nt < 4; ++nt)
                    acc[mt][nt] = __builtin_amdgcn_mfma_f32_16x16x32_bf16(
                        av[mt], bv[nt], acc[mt][nt], 0, 0, 0);
        }
        __syncthreads();
    }

    int rh = lane >> 4;
#pragma unroll
    for (int mt = 0; mt < 4; ++mt)
#pragma unroll
        for (int nt = 0; nt < 4; ++nt)
#pragma unroll
            for (int rr = 0; rr < 4; ++rr) {
                size_t grow = row0 + wr * 64 + mt * 16 + rh * 4 + rr;
                int c = c0 + wc * 64 + nt * 16 + rl;
                float v = acc[mt][nt][rr];
                if (OP == 1) {
                    ((float*)Cptr)[grow * 512 + c] += v + Bbase[(size_t)e * bestride + c];
                } else {
                    float vb = v + Bbase[(size_t)e * bestride + c];
                    float gl = vb * 0.5f * (1.f + erff(vb * 0.70710678118f));
                    ((u16*)Cptr)[grow * 512 + (c ^ (((int)grow & 7) << 3))] = f2bf(gl);
                }
            }
}

// ---------------------------------------------------------------------------
// MFMA attention: 1-D grid 1024 (b-major so all 8 heads of an item share an
// XCD L2). 5 waves (320 thr), wave w owns m-tile w. Out st8-SWIZZLED.
// ---------------------------------------------------------------------------
#define ATT_LDS (23040 / 2 + 8320 / 2 + 12288 / 2)
__global__ __launch_bounds__(320) void attn3_k(const u16* __restrict__ qkv,
                                               u16* __restrict__ o,
                                               const int* __restrict__ prow) {
    int b = blockIdx.x & 127, h = blockIdx.x >> 7, tid = threadIdx.x;
    int pr = prow[b];
    __shared__ __align__(16) u16 smem[ATT_LDS];
    u16* Qs = smem;                    // [80][72]
    u16* Ks = smem + 80 * 72;          // [80][72]
    u16* Ps = smem;                    // [80][96]
    u16* Vs = smem + 2 * 80 * 72;      // [65][64]
    u16* Vt = Vs + 65 * 64;            // [64][96]

    const u16* base = qkv + (size_t)pr * 1536 + h * 64;

    for (int idx = tid; idx < 640; idx += 320) {
        int r = idx >> 3, q = idx & 7;
        int4 vq = {0, 0, 0, 0}, vk = {0, 0, 0, 0};
        if (r < NTOK) {
            vq = *(const int4*)&base[(size_t)r * 1536 + q * 8];
            vk = *(const int4*)&base[(size_t)r * 1536 + 512 + q * 8];
        }
        *(int4*)&Qs[r * 72 + q * 8] = vq;
        *(int4*)&Ks[r * 72 + q * 8] = vk;
    }
    for (int idx = tid; idx < 520; idx += 320) {
        int r = idx >> 3, q = idx & 7;
        *(int4*)&Vs[r * 64 + q * 8] = *(const int4*)&base[(size_t)r * 1536 + 1024 + q * 8];
    }
    __syncthreads();

    int lane = tid & 63, mt = tid >> 6;
    int rl = lane & 15, kg = lane >> 4, g = lane >> 4;

    f32x4 acc[5];
#pragma unroll
    for (int nt = 0; nt < 5; ++nt) acc[nt] = (f32x4){0.f, 0.f, 0.f, 0.f};

    {
        bf16x8 av0 = *(const bf16x8*)&Qs[(mt * 16 + rl) * 72 + kg * 8];
        bf16x8 av1 = *(const bf16x8*)&Qs[(mt * 16 + rl) * 72 + 32 + kg * 8];
#pragma unroll
        for (int nt = 0; nt < 5; ++nt) {
            bf16x8 bv0 = *(const bf16x8*)&Ks[(nt * 16 + rl) * 72 + kg * 8];
            bf16x8 bv1 = *(const bf16x8*)&Ks[(nt * 16 + rl) * 72 + 32 + kg * 8];
            acc[nt] = __builtin_amdgcn_mfma_f32_16x16x32_bf16(av0, bv0, acc[nt], 0, 0, 0);
            acc[nt] = __builtin_amdgcn_mfma_f32_16x16x32_bf16(av1, bv1, acc[nt], 0, 0, 0);
        }
    }

    for (int idx = tid; idx < 768; idx += 320) {
        int d = idx & 63, kq = idx >> 6;
        u16 tmp[8];
#pragma unroll
        for (int j = 0; j < 8; ++j) {
            int k = kq * 8 + j;
            tmp[j] = (k < NTOK) ? Vs[k * 64 + d] : (u16)0;
        }
        *(int4*)&Vt[d * 96 + kq * 8] = *(int4*)tmp;
    }

#pragma unroll
    for (int r = 0; r < 4; ++r) {
        float m = -3.0e38f;
#pragma unroll
        for (int nt = 0; nt < 5; ++nt) {
            float s = acc[nt][r] * 0.125f;
            if (nt * 16 + rl >= NTOK) s = -3.0e38f;
            acc[nt][r] = s;
            m = fmaxf(m, s);
        }
        m = fmaxf(m, __shfl_xor(m, 1));
        m = fmaxf(m, __shfl_xor(m, 2));
        m = fmaxf(m, __shfl_xor(m, 4));
        m = fmaxf(m, __shfl_xor(m, 8));
        float sum = 0.f;
#pragma unroll
        for (int nt = 0; nt < 5; ++nt) {
            float p = expf(acc[nt][r] - m);
            acc[nt][r] = p;
            sum += p;
        }
        sum += __shfl_xor(sum, 1);
        sum += __shfl_xor(sum, 2);
        sum += __shfl_xor(sum, 4);
        sum += __shfl_xor(sum, 8);
        float inv = 1.f / sum;
#pragma unroll
        for (int nt = 0; nt < 5; ++nt) acc[nt][r] *= inv;
    }
    __syncthreads();

#pragma unroll
    for (int nt = 0; nt < 5; ++nt)
#pragma unroll
        for (int r = 0; r < 4; ++r)
            Ps[(mt * 16 + g * 4 + r) * 96 + nt * 16 + rl] = f2bf(acc[nt][r]);
    for (int idx = tid; idx < 160; idx += 320) {
        int r = idx >> 1, hf = idx & 1;
        *(int4*)&Ps[r * 96 + 80 + hf * 8] = (int4){0, 0, 0, 0};
    }
    __syncthreads();

#pragma unroll
    for (int dt = 0; dt < 4; ++dt) {
        f32x4 oa = {0.f, 0.f, 0.f, 0.f};
#pragma unroll
        for (int s2 = 0; s2 < 3; ++s2) {
            bf16x8 av = *(const bf16x8*)&Ps[(mt * 16 + rl) * 96 + s2 * 32 + kg * 8];
            bf16x8 bv = *(const bf16x8*)&Vt[(dt * 16 + rl) * 96 + s2 * 32 + kg * 8];
            oa = __builtin_amdgcn_mfma_f32_16x16x32_bf16(av, bv, oa, 0, 0, 0);
        }
#pragma unroll
        for (int r = 0; r < 4; ++r) {
            int row = mt * 16 + g * 4 + r;
            if (row < NTOK) {
                int grow = pr + row;
                int c = h * 64 + dt * 16 + rl;
                o[(size_t)grow * DIM + (c ^ ((grow & 7) << 3))] = f2bf(oa[r]);
            }
        }
    }
}

// ---------------------------------------------------------------------------
// Final LN (token 0) + head (fp32)
// ---------------------------------------------------------------------------
__global__ __launch_bounds__(64) void final_k(const float* __restrict__ t,
                                              const float* __restrict__ fg,
                                              const float* __restrict__ fb,
                                              const float* __restrict__ hw,
                                              const float* __restrict__ hb,
                                              const int* __restrict__ top1,
                                              const int* __restrict__ prow,
                                              float* __restrict__ out) {
    int b = blockIdx.x, lane = threadIdx.x;
    int e = top1[b];
    const float* row = t + (size_t)prow[b] * DIM;
    float v[8], s = 0.f, q = 0.f;
#pragma unroll
    for (int ii = 0; ii < 8; ++ii) {
        v[ii] = row[ii * 64 + lane];
        s += v[ii];
        q += v[ii] * v[ii];
    }
    for (int off = 32; off > 0; off >>= 1) {
        s += __shfl_xor(s, off);
        q += __shfl_xor(q, off);
    }
    float mean = s * (1.f / DIM);
    float var = q * (1.f / DIM) - mean * mean;
    float rs = rsqrtf(var + 1e-5f);
    float nv[8];
#pragma unroll
    for (int ii = 0; ii < 8; ++ii) {
        int d = ii * 64 + lane;
        nv[ii] = (v[ii] - mean) * rs * fg[e * DIM + d] + fb[e * DIM + d];
    }
    for (int c = 0; c < NCLS; ++c) {
        float p = 0.f;
#pragma unroll
        for (int ii = 0; ii < 8; ++ii) {
            int d = ii * 64 + lane;
            p = fmaf(nv[ii], hw[(size_t)e * DIM * NCLS + d * NCLS + c], p);
        }
        for (int off = 32; off > 0; off >>= 1) p += __shfl_xor(p, off);
        if (lane == 0) out[b * NCLS + c] = p + hb[e * NCLS + c];
    }
}

// ---------------------------------------------------------------------------
extern "C" void kernel_launch(void* const* d_in, const int* in_sizes, int n_in,
                              void* d_out, int out_size, void* d_ws, size_t ws_size,
                              hipStream_t stream) {
    const float* x       = (const float*)d_in[0];
    const float* gate_w  = (const float*)d_in[1];
    const float* gate_b  = (const float*)d_in[2];
    const float* pln1_g  = (const float*)d_in[3];
    const float* pln1_b  = (const float*)d_in[4];
    const float* patch_w = (const float*)d_in[5];
    const float* patch_b = (const float*)d_in[6];
    const float* pln2_g  = (const float*)d_in[7];
    const float* pln2_b  = (const float*)d_in[8];
    const float* cls_tok = (const float*)d_in[9];
    const float* pos_emb = (const float*)d_in[10];
    const float* aln_g   = (const float*)d_in[11];
    const float* aln_b   = (const float*)d_in[12];
    const float* qkv_w   = (const float*)d_in[13];
    const float* out_w   = (const float*)d_in[14];
    const float* out_b   = (const float*)d_in[15];
    const float* fln_g   = (const float*)d_in[16];
    const float* fln_b   = (const float*)d_in[17];
    const float* ff1_w   = (const float*)d_in[18];
    const float* ff1_b   = (const float*)d_in[19];
    const float* ff2_w   = (const float*)d_in[20];
    const float* ff2_b   = (const float*)d_in[21];
    const float* final_g = (const float*)d_in[22];
    const float* final_b = (const float*)d_in[23];
    const float* head_w  = (const float*)d_in[24];
    const float* head_b  = (const float*)d_in[25];
    float* out = (float*)d_out;

    // Workspace (~85 MB of ~600 MB)
    int* top1   = (int*)d_ws;                                // 128
    int* prow   = top1 + 128;                                // 128
    int* tile_e = prow + 128;                                // 40 (pad)
    float* t  = (float*)((char*)d_ws + 4096);                // fp32 [NROWSP][512] linear
    u16* aln  = (u16*)(t + (size_t)NROWSP * DIM);            // bf16 [NROWSP][512] SWZ
    u16* qb16 = aln + (size_t)NROWSP * DIM;                  // bf16 [NROWSP][1536] linear
    u16* ao16 = qb16 + (size_t)NROWSP * 1536;                // bf16 [NROWSP][512] SWZ
    u16* h16  = ao16 + (size_t)NROWSP * DIM;                 // bf16 [NROWSP][512] SWZ

    gate_k<<<BATCH, 256, 0, stream>>>(x, gate_w, gate_b, top1);
    route3_k<<<1, 128, 0, stream>>>(top1, prow, tile_e);
    patch_k<<<dim3(NTOK, BATCH), 256, 0, stream>>>(x, pln1_g, pln1_b, patch_w, patch_b,
                                                   pln2_g, pln2_b, cls_tok, pos_emb,
                                                   top1, prow, t);

    for (int l = 0; l < DEPTH; ++l) {
        ln2_k<<<NROWSP / 4, 256, 0, stream>>>(t, aln, aln_g + l * DIM, aln_b + l * DIM,
                                              tile_e, DEPTH * DIM);
        mgemm6_k<<<NRT256 * 12, 512, 0, stream>>>(
            aln, qkv_w + (size_t)l * 512 * 1536, qb16, tile_e,
            DEPTH * 512 * 1536);
        attn3_k<<<HEADS * BATCH, 320, 0, stream>>>(qb16, ao16, prow);
        mgemm5_k<1><<<NRT128 * 4, 256, 0, stream>>>(
            ao16, out_w + (size_t)l * 512 * 512, out_b + l * DIM, t, tile_e,
            DEPTH * 512 * 512, DEPTH * DIM);
        ln2_k<<<NROWSP / 4, 256, 0, stream>>>(t, aln, fln_g + l * DIM, fln_b + l * DIM,
                                              tile_e, DEPTH * DIM);
        mgemm5_k<2><<<NRT128 * 4, 256, 0, stream>>>(
            aln, ff1_w + (size_t)l * 512 * 512, ff1_b + l * DIM, h16, tile_e,
            DEPTH * 512 * 512, DEPTH * DIM);
        mgemm5_k<1><<<NRT128 * 4, 256, 0, stream>>>(
            h16, ff2_w + (size_t)l * 512 * 512, ff2_b + l * DIM, t, tile_e,
            DEPTH * 512 * 512, DEPTH * DIM);
    }
    final_k<<<BATCH, 64, 0, stream>>>(t, final_g, final_b, head_w, head_b, top1, prow, out);
}

// Round 12
// 812.606 us; speedup vs baseline: 1.3531x; 1.1967x over previous
//
#include <hip/hip_runtime.h>
#include <math.h>

#define EXPERTS 8
#define DEPTH 6
#define DIM 512
#define HEADS 8
#define NCLS 10
#define BATCH 128
#define PD 48
#define NTOK 65
#define NRT256 40              // max 256-row tiles
#define NROWSP (NRT256 * 256)  // 10240 gathered rows

typedef __attribute__((ext_vector_type(4))) float f32x4;
typedef __attribute__((ext_vector_type(8))) __bf16 bf16x8;
typedef unsigned short u16;

#define GLOAD_LDS16(gp, lp)                                                     \
    __builtin_amdgcn_global_load_lds(                                           \
        (const __attribute__((address_space(1))) void*)(gp),                    \
        (__attribute__((address_space(3))) void*)(lp), 16, 0, 0)

__device__ inline u16 f2bf(float f) {
    union { float f; unsigned u; } v; v.f = f;
    unsigned r = v.u + 0x7FFFu + ((v.u >> 16) & 1u);
    return (u16)(r >> 16);
}

// ---------------------------------------------------------------------------
// Gate (exact fp32 — routing must not flip)
// ---------------------------------------------------------------------------
__global__ __launch_bounds__(256) void gate_k(const float* __restrict__ x,
                                              const float* __restrict__ gw,
                                              const float* __restrict__ gb,
                                              int* __restrict__ top1) {
    int b = blockIdx.x, tid = threadIdx.x;
    const float* xb = x + (size_t)b * 3072;
    float acc[EXPERTS];
#pragma unroll
    for (int e = 0; e < EXPERTS; ++e) acc[e] = 0.f;
    for (int i = tid; i < 3072; i += 256) {
        float xv = xb[i];
#pragma unroll
        for (int e = 0; e < EXPERTS; ++e)
            acc[e] = fmaf(xv, gw[(size_t)e * 3072 + i], acc[e]);
    }
    __shared__ float red[256];
    __shared__ float logits[EXPERTS];
    for (int e = 0; e < EXPERTS; ++e) {
        red[tid] = acc[e];
        __syncthreads();
        for (int s = 128; s > 0; s >>= 1) {
            if (tid < s) red[tid] += red[tid + s];
            __syncthreads();
        }
        if (tid == 0) logits[e] = red[0] + gb[e];
        __syncthreads();
    }
    if (tid == 0) {
        int best = 0;
        float bv = logits[0];
        for (int e = 1; e < EXPERTS; ++e)
            if (logits[e] > bv) { bv = logits[e]; best = e; }
        top1[b] = best;
    }
}

// ---------------------------------------------------------------------------
// Routing: gathered rows, experts padded to 256-row tiles.
// ---------------------------------------------------------------------------
__global__ __launch_bounds__(128) void route3_k(const int* __restrict__ top1,
                                                int* __restrict__ prow,
                                                int* __restrict__ tile_e) {
    __shared__ int t1[BATCH];
    int tid = threadIdx.x;
    t1[tid] = top1[tid];
    __syncthreads();
    if (tid != 0) return;
    int row = 0, tile = 0;
    for (int e = 0; e < EXPERTS; ++e) {
        int ne = 0;
        for (int b = 0; b < BATCH; ++b)
            if (t1[b] == e) { prow[b] = row + ne * 65; ne++; }
        if (!ne) continue;
        int nt = (ne * 65 + 255) >> 8;
        for (int tt = 0; tt < nt; ++tt) tile_e[tile++] = e;
        row += nt << 8;
    }
    for (; tile < NRT256; ++tile) tile_e[tile] = -1;
}

// ---------------------------------------------------------------------------
// Patch embed (fp32, writes gathered residual stream t, linear)
// ---------------------------------------------------------------------------
__global__ __launch_bounds__(256) void patch_k(const float* __restrict__ x,
                                               const float* __restrict__ pln1_g,
                                               const float* __restrict__ pln1_b,
                                               const float* __restrict__ patch_w,
                                               const float* __restrict__ patch_b,
                                               const float* __restrict__ pln2_g,
                                               const float* __restrict__ pln2_b,
                                               const float* __restrict__ cls_tok,
                                               const float* __restrict__ pos_emb,
                                               const int* __restrict__ top1,
                                               const int* __restrict__ prow,
                                               float* __restrict__ t) {
    int n = blockIdx.x, b = blockIdx.y, tid = threadIdx.x;
    int e = top1[b];
    float* trow = t + ((size_t)prow[b] + n) * DIM;
    const float* pe = pos_emb + ((size_t)e * NTOK + n) * DIM;

    if (n == 0) {
        for (int d = tid; d < DIM; d += 256)
            trow[d] = cls_tok[e * DIM + d] + pe[d];
        return;
    }
    int pi = n - 1, h = pi >> 3, w = pi & 7;
    __shared__ float pv[PD];
    __shared__ float red[256];
    if (tid < PD) {
        int p1 = tid / 12, rem = tid % 12, p2 = rem / 3, c = rem % 3;
        pv[tid] = x[((size_t)b * 3 + c) * 1024 + (h * 4 + p1) * 32 + (w * 4 + p2)];
    }
    __syncthreads();
    float m = 0.f, q = 0.f;
    for (int j = 0; j < PD; ++j) { float v = pv[j]; m += v; q += v * v; }
    m *= (1.f / PD);
    q = q * (1.f / PD) - m * m;
    float rs = rsqrtf(q + 1e-5f);
    __syncthreads();
    if (tid < PD)
        pv[tid] = (pv[tid] - m) * rs * pln1_g[e * PD + tid] + pln1_b[e * PD + tid];
    __syncthreads();

    float acc0 = patch_b[e * DIM + tid];
    float acc1 = patch_b[e * DIM + tid + 256];
    for (int j = 0; j < PD; ++j) {
        float v = pv[j];
        const float* wr = patch_w + ((size_t)e * PD + j) * DIM;
        acc0 = fmaf(v, wr[tid], acc0);
        acc1 = fmaf(v, wr[tid + 256], acc1);
    }
    red[tid] = acc0 + acc1;
    __syncthreads();
    for (int s = 128; s > 0; s >>= 1) {
        if (tid < s) red[tid] += red[tid + s];
        __syncthreads();
    }
    float S = red[0];
    __syncthreads();
    red[tid] = acc0 * acc0 + acc1 * acc1;
    __syncthreads();
    for (int s = 128; s > 0; s >>= 1) {
        if (tid < s) red[tid] += red[tid + s];
        __syncthreads();
    }
    float Q = red[0];
    float mean = S * (1.f / DIM);
    float var = Q * (1.f / DIM) - mean * mean;
    float rs2 = rsqrtf(var + 1e-5f);
    trow[tid]       = (acc0 - mean) * rs2 * pln2_g[e * DIM + tid]       + pln2_b[e * DIM + tid]       + pe[tid];
    trow[tid + 256] = (acc1 - mean) * rs2 * pln2_g[e * DIM + tid + 256] + pln2_b[e * DIM + tid + 256] + pe[tid + 256];
}

// ---------------------------------------------------------------------------
// LayerNorm over gathered rows: fp32 t (linear) -> bf16 dst (st8-SWIZZLED).
// ---------------------------------------------------------------------------
__global__ __launch_bounds__(256) void ln2_k(const float* __restrict__ src,
                                             u16* __restrict__ dst,
                                             const float* __restrict__ gbase,
                                             const float* __restrict__ bbase,
                                             const int* __restrict__ tile_e,
                                             int gestride) {
    int row = blockIdx.x * 4 + (threadIdx.x >> 6);
    int lane = threadIdx.x & 63;
    int e = tile_e[row >> 8];
    if (e < 0) return;
    const float* s = src + (size_t)row * 512;
    float4 a = *(const float4*)&s[lane * 4];
    float4 b = *(const float4*)&s[256 + lane * 4];
    float sum = a.x + a.y + a.z + a.w + b.x + b.y + b.z + b.w;
    float sq = a.x * a.x + a.y * a.y + a.z * a.z + a.w * a.w +
               b.x * b.x + b.y * b.y + b.z * b.z + b.w * b.w;
#pragma unroll
    for (int off = 32; off > 0; off >>= 1) {
        sum += __shfl_xor(sum, off);
        sq += __shfl_xor(sq, off);
    }
    float mean = sum * (1.f / DIM);
    float rs = rsqrtf(sq * (1.f / DIM) - mean * mean + 1e-5f);
    const float* g = gbase + (size_t)e * gestride;
    const float* bb = bbase + (size_t)e * gestride;
    float4 g0 = *(const float4*)&g[lane * 4];
    float4 g1 = *(const float4*)&g[256 + lane * 4];
    float4 b0 = *(const float4*)&bb[lane * 4];
    float4 b1 = *(const float4*)&bb[256 + lane * 4];
    int swz = (row & 7) << 3;
    u16 o[4];
    o[0] = f2bf((a.x - mean) * rs * g0.x + b0.x);
    o[1] = f2bf((a.y - mean) * rs * g0.y + b0.y);
    o[2] = f2bf((a.z - mean) * rs * g0.z + b0.z);
    o[3] = f2bf((a.w - mean) * rs * g0.w + b0.w);
    *(int2*)&dst[(size_t)row * 512 + ((lane * 4) ^ swz)] = *(int2*)o;
    o[0] = f2bf((b.x - mean) * rs * g1.x + b1.x);
    o[1] = f2bf((b.y - mean) * rs * g1.y + b1.y);
    o[2] = f2bf((b.z - mean) * rs * g1.z + b1.z);
    o[3] = f2bf((b.w - mean) * rs * g1.w + b1.w);
    *(int2*)&dst[(size_t)row * 512 + ((256 + lane * 4) ^ swz)] = *(int2*)o;
}

// ---------------------------------------------------------------------------
// Weight convert fp32 [512][N] -> bf16 [N][512] transposed + st8-swizzled.
// ---------------------------------------------------------------------------
__device__ inline void wconv_body(const float* __restrict__ s,
                                  u16* __restrict__ d, int N,
                                  int n0, int k0, int tid) {
    __shared__ float tile[32][33];
    int r = tid >> 5, c = tid & 31;
#pragma unroll
    for (int i = 0; i < 4; ++i)
        tile[r + i * 8][c] = s[(size_t)(k0 + r + i * 8) * N + n0 + c];
    __syncthreads();
#pragma unroll
    for (int i = 0; i < 4; ++i) {
        int n = n0 + r + i * 8;
        d[(size_t)n * 512 + ((k0 + c) ^ ((n & 7) << 3))] = f2bf(tile[c][r + i * 8]);
    }
}

__global__ __launch_bounds__(256) void wconv_k(const float* __restrict__ src,
                                               u16* __restrict__ dst, int N) {
    wconv_body(src + (size_t)blockIdx.z * 512 * N, dst + (size_t)blockIdx.z * 512 * N,
               N, blockIdx.x * 32, blockIdx.y * 32, threadIdx.x);
}

// one launch for the three 512-wide weight sets; grid (16,16,144)
__global__ __launch_bounds__(256) void wconv3_k(const float* __restrict__ s0,
                                                const float* __restrict__ s1,
                                                const float* __restrict__ s2,
                                                u16* __restrict__ d0,
                                                u16* __restrict__ d1,
                                                u16* __restrict__ d2) {
    int z = blockIdx.z, which = z / 48, m = z % 48;
    const float* s = (which == 0) ? s0 : (which == 1) ? s1 : s2;
    u16* d = (which == 0) ? d0 : (which == 1) ? d1 : d2;
    wconv_body(s + (size_t)m * 512 * 512, d + (size_t)m * 512 * 512,
               512, blockIdx.x * 32, blockIdx.y * 32, threadIdx.x);
}

// ---------------------------------------------------------------------------
// Generic batched MFMA GEMM over gathered rows, m97 recipe.
// Block = (MW*32) rows x 128 cols, 4 waves (2x2), wave tile = (MW*16) x 64.
//   MW=4 -> 128x128 (qkv, grid 960); MW=2 -> 64x128 (512s, grid 640).
// A: global_load_lds from pre-swizzled bf16; B: same from converted weights.
// OP: 0 = store bf16 linear; 1 = fp32 t += acc+bias; 2 = bias+GELU -> SWZ bf16
// ---------------------------------------------------------------------------
template <int N, int OP, int MW>
__global__ __launch_bounds__(256) void mgemm_k(const u16* __restrict__ A,
                                               const u16* __restrict__ Wtbase,
                                               const float* __restrict__ Bbase,
                                               void* __restrict__ Cptr,
                                               const int* __restrict__ tile_e,
                                               int westride, int bestride) {
    constexpr int M = MW * 32;
    constexpr int CT = N / 128;
    constexpr int MTILES = NROWSP / M;
    int orig = blockIdx.x, nwg = MTILES * CT;
    int q = nwg >> 3, r8 = nwg & 7;
    int xcd = orig & 7, off = orig >> 3;
    int wg = (xcd < r8 ? xcd * (q + 1) : r8 * (q + 1) + (xcd - r8) * q) + off;
    int tile = wg / CT, ct = wg - tile * CT;
    int e = tile_e[(tile * M) >> 8];
    if (e < 0) return;
    int row0 = tile * M, c0 = ct * 128;
    const u16* Wt = Wtbase + (size_t)e * westride;

    int tid = threadIdx.x;
    int lane = tid & 63, w = tid >> 6;
    int rl = lane & 15, kg = lane >> 4;
    int wr = w >> 1, wc = w & 1;

    __shared__ __align__(16) u16 As[M * 64];
    __shared__ __align__(16) u16 Bs[128 * 64];

    f32x4 acc[MW][4];
#pragma unroll
    for (int mt = 0; mt < MW; ++mt)
#pragma unroll
        for (int nt = 0; nt < 4; ++nt) acc[mt][nt] = (f32x4){0.f, 0.f, 0.f, 0.f};

    const u16* Ag = A + (size_t)(row0 + w * (M / 4) + (lane >> 3)) * 512 + (lane & 7) * 8;
    const u16* Bg = Wt + (size_t)(c0 + w * 32 + (lane >> 3)) * 512 + (lane & 7) * 8;
    u16* Asw = As + w * (M / 4) * 64;
    u16* Bsw = Bs + w * 2048;

    int blk0 = (kg ^ (rl & 7)) * 8;
    int blk1 = ((4 + kg) ^ (rl & 7)) * 8;

    for (int k0 = 0; k0 < 512; k0 += 64) {
#pragma unroll
        for (int i = 0; i < M / 32; ++i)
            GLOAD_LDS16(Ag + k0 + i * 8 * 512, Asw + i * 512);
#pragma unroll
        for (int i = 0; i < 4; ++i)
            GLOAD_LDS16(Bg + k0 + i * 8 * 512, Bsw + i * 512);
        __syncthreads();
#pragma unroll
        for (int ks = 0; ks < 2; ++ks) {
            int blk = ks ? blk1 : blk0;
            bf16x8 av[MW], bv[4];
#pragma unroll
            for (int i = 0; i < MW; ++i)
                av[i] = *(const bf16x8*)&As[(wr * (M / 2) + i * 16 + rl) * 64 + blk];
#pragma unroll
            for (int i = 0; i < 4; ++i)
                bv[i] = *(const bf16x8*)&Bs[(wc * 64 + i * 16 + rl) * 64 + blk];
#pragma unroll
            for (int mt = 0; mt < MW; ++mt)
#pragma unroll
                for (int nt = 0; nt < 4; ++nt)
                    acc[mt][nt] = __builtin_amdgcn_mfma_f32_16x16x32_bf16(
                        av[mt], bv[nt], acc[mt][nt], 0, 0, 0);
        }
        __syncthreads();
    }

    int rh = lane >> 4;
#pragma unroll
    for (int mt = 0; mt < MW; ++mt)
#pragma unroll
        for (int nt = 0; nt < 4; ++nt)
#pragma unroll
            for (int rr = 0; rr < 4; ++rr) {
                size_t grow = row0 + wr * (M / 2) + mt * 16 + rh * 4 + rr;
                int c = c0 + wc * 64 + nt * 16 + rl;
                float v = acc[mt][nt][rr];
                if (OP == 0) {
                    ((u16*)Cptr)[grow * N + c] = f2bf(v);
                } else if (OP == 1) {
                    ((float*)Cptr)[grow * 512 + c] += v + Bbase[(size_t)e * bestride + c];
                } else {
                    float vb = v + Bbase[(size_t)e * bestride + c];
                    float gl = vb * 0.5f * (1.f + erff(vb * 0.70710678118f));
                    ((u16*)Cptr)[grow * 512 + (c ^ (((int)grow & 7) << 3))] = f2bf(gl);
                }
            }
}

// ---------------------------------------------------------------------------
// MFMA attention: 1-D grid 1024 (b-major). 5 waves, wave w owns m-tile w.
// qkv (linear) in, out st8-SWIZZLED.
// ---------------------------------------------------------------------------
#define ATT_LDS (23040 / 2 + 8320 / 2 + 12288 / 2)
__global__ __launch_bounds__(320) void attn3_k(const u16* __restrict__ qkv,
                                               u16* __restrict__ o,
                                               const int* __restrict__ prow) {
    int b = blockIdx.x & 127, h = blockIdx.x >> 7, tid = threadIdx.x;
    int pr = prow[b];
    __shared__ __align__(16) u16 smem[ATT_LDS];
    u16* Qs = smem;                    // [80][72]
    u16* Ks = smem + 80 * 72;          // [80][72]
    u16* Ps = smem;                    // [80][96]
    u16* Vs = smem + 2 * 80 * 72;      // [65][64]
    u16* Vt = Vs + 65 * 64;            // [64][96]

    const u16* base = qkv + (size_t)pr * 1536 + h * 64;

    for (int idx = tid; idx < 640; idx += 320) {
        int r = idx >> 3, q = idx & 7;
        int4 vq = {0, 0, 0, 0}, vk = {0, 0, 0, 0};
        if (r < NTOK) {
            vq = *(const int4*)&base[(size_t)r * 1536 + q * 8];
            vk = *(const int4*)&base[(size_t)r * 1536 + 512 + q * 8];
        }
        *(int4*)&Qs[r * 72 + q * 8] = vq;
        *(int4*)&Ks[r * 72 + q * 8] = vk;
    }
    for (int idx = tid; idx < 520; idx += 320) {
        int r = idx >> 3, q = idx & 7;
        *(int4*)&Vs[r * 64 + q * 8] = *(const int4*)&base[(size_t)r * 1536 + 1024 + q * 8];
    }
    __syncthreads();

    int lane = tid & 63, mt = tid >> 6;
    int rl = lane & 15, kg = lane >> 4, g = lane >> 4;

    f32x4 acc[5];
#pragma unroll
    for (int nt = 0; nt < 5; ++nt) acc[nt] = (f32x4){0.f, 0.f, 0.f, 0.f};

    {
        bf16x8 av0 = *(const bf16x8*)&Qs[(mt * 16 + rl) * 72 + kg * 8];
        bf16x8 av1 = *(const bf16x8*)&Qs[(mt * 16 + rl) * 72 + 32 + kg * 8];
#pragma unroll
        for (int nt = 0; nt < 5; ++nt) {
            bf16x8 bv0 = *(const bf16x8*)&Ks[(nt * 16 + rl) * 72 + kg * 8];
            bf16x8 bv1 = *(const bf16x8*)&Ks[(nt * 16 + rl) * 72 + 32 + kg * 8];
            acc[nt] = __builtin_amdgcn_mfma_f32_16x16x32_bf16(av0, bv0, acc[nt], 0, 0, 0);
            acc[nt] = __builtin_amdgcn_mfma_f32_16x16x32_bf16(av1, bv1, acc[nt], 0, 0, 0);
        }
    }

    for (int idx = tid; idx < 768; idx += 320) {
        int d = idx & 63, kq = idx >> 6;
        u16 tmp[8];
#pragma unroll
        for (int j = 0; j < 8; ++j) {
            int k = kq * 8 + j;
            tmp[j] = (k < NTOK) ? Vs[k * 64 + d] : (u16)0;
        }
        *(int4*)&Vt[d * 96 + kq * 8] = *(int4*)tmp;
    }

#pragma unroll
    for (int r = 0; r < 4; ++r) {
        float m = -3.0e38f;
#pragma unroll
        for (int nt = 0; nt < 5; ++nt) {
            float s = acc[nt][r] * 0.125f;
            if (nt * 16 + rl >= NTOK) s = -3.0e38f;
            acc[nt][r] = s;
            m = fmaxf(m, s);
        }
        m = fmaxf(m, __shfl_xor(m, 1));
        m = fmaxf(m, __shfl_xor(m, 2));
        m = fmaxf(m, __shfl_xor(m, 4));
        m = fmaxf(m, __shfl_xor(m, 8));
        float sum = 0.f;
#pragma unroll
        for (int nt = 0; nt < 5; ++nt) {
            float p = expf(acc[nt][r] - m);
            acc[nt][r] = p;
            sum += p;
        }
        sum += __shfl_xor(sum, 1);
        sum += __shfl_xor(sum, 2);
        sum += __shfl_xor(sum, 4);
        sum += __shfl_xor(sum, 8);
        float inv = 1.f / sum;
#pragma unroll
        for (int nt = 0; nt < 5; ++nt) acc[nt][r] *= inv;
    }
    __syncthreads();

#pragma unroll
    for (int nt = 0; nt < 5; ++nt)
#pragma unroll
        for (int r = 0; r < 4; ++r)
            Ps[(mt * 16 + g * 4 + r) * 96 + nt * 16 + rl] = f2bf(acc[nt][r]);
    for (int idx = tid; idx < 160; idx += 320) {
        int r = idx >> 1, hf = idx & 1;
        *(int4*)&Ps[r * 96 + 80 + hf * 8] = (int4){0, 0, 0, 0};
    }
    __syncthreads();

#pragma unroll
    for (int dt = 0; dt < 4; ++dt) {
        f32x4 oa = {0.f, 0.f, 0.f, 0.f};
#pragma unroll
        for (int s2 = 0; s2 < 3; ++s2) {
            bf16x8 av = *(const bf16x8*)&Ps[(mt * 16 + rl) * 96 + s2 * 32 + kg * 8];
            bf16x8 bv = *(const bf16x8*)&Vt[(dt * 16 + rl) * 96 + s2 * 32 + kg * 8];
            oa = __builtin_amdgcn_mfma_f32_16x16x32_bf16(av, bv, oa, 0, 0, 0);
        }
#pragma unroll
        for (int r = 0; r < 4; ++r) {
            int row = mt * 16 + g * 4 + r;
            if (row < NTOK) {
                int grow = pr + row;
                int c = h * 64 + dt * 16 + rl;
                o[(size_t)grow * DIM + (c ^ ((grow & 7) << 3))] = f2bf(oa[r]);
            }
        }
    }
}

// ---------------------------------------------------------------------------
// Final LN (token 0) + head (fp32)
// ---------------------------------------------------------------------------
__global__ __launch_bounds__(64) void final_k(const float* __restrict__ t,
                                              const float* __restrict__ fg,
                                              const float* __restrict__ fb,
                                              const float* __restrict__ hw,
                                              const float* __restrict__ hb,
                                              const int* __restrict__ top1,
                                              const int* __restrict__ prow,
                                              float* __restrict__ out) {
    int b = blockIdx.x, lane = threadIdx.x;
    int e = top1[b];
    const float* row = t + (size_t)prow[b] * DIM;
    float v[8], s = 0.f, q = 0.f;
#pragma unroll
    for (int ii = 0; ii < 8; ++ii) {
        v[ii] = row[ii * 64 + lane];
        s += v[ii];
        q += v[ii] * v[ii];
    }
    for (int off = 32; off > 0; off >>= 1) {
        s += __shfl_xor(s, off);
        q += __shfl_xor(q, off);
    }
    float mean = s * (1.f / DIM);
    float var = q * (1.f / DIM) - mean * mean;
    float rs = rsqrtf(var + 1e-5f);
    float nv[8];
#pragma unroll
    for (int ii = 0; ii < 8; ++ii) {
        int d = ii * 64 + lane;
        nv[ii] = (v[ii] - mean) * rs * fg[e * DIM + d] + fb[e * DIM + d];
    }
    for (int c = 0; c < NCLS; ++c) {
        float p = 0.f;
#pragma unroll
        for (int ii = 0; ii < 8; ++ii) {
            int d = ii * 64 + lane;
            p = fmaf(nv[ii], hw[(size_t)e * DIM * NCLS + d * NCLS + c], p);
        }
        for (int off = 32; off > 0; off >>= 1) p += __shfl_xor(p, off);
        if (lane == 0) out[b * NCLS + c] = p + hb[e * NCLS + c];
    }
}

// ---------------------------------------------------------------------------
extern "C" void kernel_launch(void* const* d_in, const int* in_sizes, int n_in,
                              void* d_out, int out_size, void* d_ws, size_t ws_size,
                              hipStream_t stream) {
    const float* x       = (const float*)d_in[0];
    const float* gate_w  = (const float*)d_in[1];
    const float* gate_b  = (const float*)d_in[2];
    const float* pln1_g  = (const float*)d_in[3];
    const float* pln1_b  = (const float*)d_in[4];
    const float* patch_w = (const float*)d_in[5];
    const float* patch_b = (const float*)d_in[6];
    const float* pln2_g  = (const float*)d_in[7];
    const float* pln2_b  = (const float*)d_in[8];
    const float* cls_tok = (const float*)d_in[9];
    const float* pos_emb = (const float*)d_in[10];
    const float* aln_g   = (const float*)d_in[11];
    const float* aln_b   = (const float*)d_in[12];
    const float* qkv_w   = (const float*)d_in[13];
    const float* out_w   = (const float*)d_in[14];
    const float* out_b   = (const float*)d_in[15];
    const float* fln_g   = (const float*)d_in[16];
    const float* fln_b   = (const float*)d_in[17];
    const float* ff1_w   = (const float*)d_in[18];
    const float* ff1_b   = (const float*)d_in[19];
    const float* ff2_w   = (const float*)d_in[20];
    const float* ff2_b   = (const float*)d_in[21];
    const float* final_g = (const float*)d_in[22];
    const float* final_b = (const float*)d_in[23];
    const float* head_w  = (const float*)d_in[24];
    const float* head_b  = (const float*)d_in[25];
    float* out = (float*)d_out;

    // Workspace (~260 MB of ~600 MB)
    int* top1   = (int*)d_ws;                                // 128
    int* prow   = top1 + 128;                                // 128
    int* tile_e = prow + 128;                                // 40 (pad)
    float* t  = (float*)((char*)d_ws + 4096);                // fp32 [NROWSP][512] linear
    u16* aln  = (u16*)(t + (size_t)NROWSP * DIM);            // bf16 [NROWSP][512] SWZ
    u16* qb16 = aln + (size_t)NROWSP * DIM;                  // bf16 [NROWSP][1536] linear
    u16* ao16 = qb16 + (size_t)NROWSP * 1536;                // bf16 [NROWSP][512] SWZ
    u16* h16  = ao16 + (size_t)NROWSP * DIM;                 // bf16 [NROWSP][512] SWZ
    u16* wq_t = h16 + (size_t)NROWSP * DIM;                  // bf16 [48][1536][512] SWZ
    u16* wo_t = wq_t + (size_t)48 * 1536 * 512;              // bf16 [48][512][512] SWZ
    u16* w1_t = wo_t + (size_t)48 * 512 * 512;
    u16* w2_t = w1_t + (size_t)48 * 512 * 512;

    gate_k<<<BATCH, 256, 0, stream>>>(x, gate_w, gate_b, top1);
    route3_k<<<1, 128, 0, stream>>>(top1, prow, tile_e);
    patch_k<<<dim3(NTOK, BATCH), 256, 0, stream>>>(x, pln1_g, pln1_b, patch_w, patch_b,
                                                   pln2_g, pln2_b, cls_tok, pos_emb,
                                                   top1, prow, t);
    wconv_k<<<dim3(48, 16, 48), 256, 0, stream>>>(qkv_w, wq_t, 1536);
    wconv3_k<<<dim3(16, 16, 144), 256, 0, stream>>>(out_w, ff1_w, ff2_w, wo_t, w1_t, w2_t);

    for (int l = 0; l < DEPTH; ++l) {
        ln2_k<<<NROWSP / 4, 256, 0, stream>>>(t, aln, aln_g + l * DIM, aln_b + l * DIM,
                                              tile_e, DEPTH * DIM);
        mgemm_k<1536, 0, 4><<<(NROWSP / 128) * 12, 256, 0, stream>>>(
            aln, wq_t + (size_t)l * 1536 * 512, nullptr, qb16, tile_e,
            DEPTH * 512 * 1536, 0);
        attn3_k<<<HEADS * BATCH, 320, 0, stream>>>(qb16, ao16, prow);
        mgemm_k<512, 1, 2><<<(NROWSP / 64) * 4, 256, 0, stream>>>(
            ao16, wo_t + (size_t)l * 512 * 512, out_b + l * DIM, t, tile_e,
            DEPTH * 512 * 512, DEPTH * DIM);
        ln2_k<<<NROWSP / 4, 256, 0, stream>>>(t, aln, fln_g + l * DIM, fln_b + l * DIM,
                                              tile_e, DEPTH * DIM);
        mgemm_k<512, 2, 2><<<(NROWSP / 64) * 4, 256, 0, stream>>>(
            aln, w1_t + (size_t)l * 512 * 512, ff1_b + l * DIM, h16, tile_e,
            DEPTH * 512 * 512, DEPTH * DIM);
        mgemm_k<512, 1, 2><<<(NROWSP / 64) * 4, 256, 0, stream>>>(
            h16, w2_t + (size_t)l * 512 * 512, ff2_b + l * DIM, t, tile_e,
            DEPTH * 512 * 512, DEPTH * DIM);
    }
    final_k<<<BATCH, 64, 0, stream>>>(t, final_g, final_b, head_w, head_b, top1, prow, out);
}

// Round 13
// 801.991 us; speedup vs baseline: 1.3710x; 1.0132x over previous
//
#include <hip/hip_runtime.h>
#include <math.h>

#define EXPERTS 8
#define DEPTH 6
#define DIM 512
#define HEADS 8
#define NCLS 10
#define BATCH 128
#define PD 48
#define NTOK 65
#define NRT256 40              // max 256-row tiles
#define NROWSP (NRT256 * 256)  // 10240 gathered rows

typedef __attribute__((ext_vector_type(4))) float f32x4;
typedef __attribute__((ext_vector_type(8))) __bf16 bf16x8;
typedef unsigned short u16;

#define GLOAD_LDS16(gp, lp)                                                     \
    __builtin_amdgcn_global_load_lds(                                           \
        (const __attribute__((address_space(1))) void*)(gp),                    \
        (__attribute__((address_space(3))) void*)(lp), 16, 0, 0)

__device__ inline u16 f2bf(float f) {
    union { float f; unsigned u; } v; v.f = f;
    unsigned r = v.u + 0x7FFFu + ((v.u >> 16) & 1u);
    return (u16)(r >> 16);
}

// ---------------------------------------------------------------------------
// Gate (exact fp32 — routing must not flip)
// ---------------------------------------------------------------------------
__global__ __launch_bounds__(256) void gate_k(const float* __restrict__ x,
                                              const float* __restrict__ gw,
                                              const float* __restrict__ gb,
                                              int* __restrict__ top1) {
    int b = blockIdx.x, tid = threadIdx.x;
    const float* xb = x + (size_t)b * 3072;
    float acc[EXPERTS];
#pragma unroll
    for (int e = 0; e < EXPERTS; ++e) acc[e] = 0.f;
    for (int i = tid; i < 3072; i += 256) {
        float xv = xb[i];
#pragma unroll
        for (int e = 0; e < EXPERTS; ++e)
            acc[e] = fmaf(xv, gw[(size_t)e * 3072 + i], acc[e]);
    }
    __shared__ float red[256];
    __shared__ float logits[EXPERTS];
    for (int e = 0; e < EXPERTS; ++e) {
        red[tid] = acc[e];
        __syncthreads();
        for (int s = 128; s > 0; s >>= 1) {
            if (tid < s) red[tid] += red[tid + s];
            __syncthreads();
        }
        if (tid == 0) logits[e] = red[0] + gb[e];
        __syncthreads();
    }
    if (tid == 0) {
        int best = 0;
        float bv = logits[0];
        for (int e = 1; e < EXPERTS; ++e)
            if (logits[e] > bv) { bv = logits[e]; best = e; }
        top1[b] = best;
    }
}

// ---------------------------------------------------------------------------
// Routing: gathered rows, experts padded to 256-row tiles.
// ---------------------------------------------------------------------------
__global__ __launch_bounds__(128) void route3_k(const int* __restrict__ top1,
                                                int* __restrict__ prow,
                                                int* __restrict__ tile_e) {
    __shared__ int t1[BATCH];
    int tid = threadIdx.x;
    t1[tid] = top1[tid];
    __syncthreads();
    if (tid != 0) return;
    int row = 0, tile = 0;
    for (int e = 0; e < EXPERTS; ++e) {
        int ne = 0;
        for (int b = 0; b < BATCH; ++b)
            if (t1[b] == e) { prow[b] = row + ne * 65; ne++; }
        if (!ne) continue;
        int nt = (ne * 65 + 255) >> 8;
        for (int tt = 0; tt < nt; ++tt) tile_e[tile++] = e;
        row += nt << 8;
    }
    for (; tile < NRT256; ++tile) tile_e[tile] = -1;
}

// ---------------------------------------------------------------------------
// Patch embed (fp32, writes gathered residual stream t, linear)
// ---------------------------------------------------------------------------
__global__ __launch_bounds__(256) void patch_k(const float* __restrict__ x,
                                               const float* __restrict__ pln1_g,
                                               const float* __restrict__ pln1_b,
                                               const float* __restrict__ patch_w,
                                               const float* __restrict__ patch_b,
                                               const float* __restrict__ pln2_g,
                                               const float* __restrict__ pln2_b,
                                               const float* __restrict__ cls_tok,
                                               const float* __restrict__ pos_emb,
                                               const int* __restrict__ top1,
                                               const int* __restrict__ prow,
                                               float* __restrict__ t) {
    int n = blockIdx.x, b = blockIdx.y, tid = threadIdx.x;
    int e = top1[b];
    float* trow = t + ((size_t)prow[b] + n) * DIM;
    const float* pe = pos_emb + ((size_t)e * NTOK + n) * DIM;

    if (n == 0) {
        for (int d = tid; d < DIM; d += 256)
            trow[d] = cls_tok[e * DIM + d] + pe[d];
        return;
    }
    int pi = n - 1, h = pi >> 3, w = pi & 7;
    __shared__ float pv[PD];
    __shared__ float red[256];
    if (tid < PD) {
        int p1 = tid / 12, rem = tid % 12, p2 = rem / 3, c = rem % 3;
        pv[tid] = x[((size_t)b * 3 + c) * 1024 + (h * 4 + p1) * 32 + (w * 4 + p2)];
    }
    __syncthreads();
    float m = 0.f, q = 0.f;
    for (int j = 0; j < PD; ++j) { float v = pv[j]; m += v; q += v * v; }
    m *= (1.f / PD);
    q = q * (1.f / PD) - m * m;
    float rs = rsqrtf(q + 1e-5f);
    __syncthreads();
    if (tid < PD)
        pv[tid] = (pv[tid] - m) * rs * pln1_g[e * PD + tid] + pln1_b[e * PD + tid];
    __syncthreads();

    float acc0 = patch_b[e * DIM + tid];
    float acc1 = patch_b[e * DIM + tid + 256];
    for (int j = 0; j < PD; ++j) {
        float v = pv[j];
        const float* wr = patch_w + ((size_t)e * PD + j) * DIM;
        acc0 = fmaf(v, wr[tid], acc0);
        acc1 = fmaf(v, wr[tid + 256], acc1);
    }
    red[tid] = acc0 + acc1;
    __syncthreads();
    for (int s = 128; s > 0; s >>= 1) {
        if (tid < s) red[tid] += red[tid + s];
        __syncthreads();
    }
    float S = red[0];
    __syncthreads();
    red[tid] = acc0 * acc0 + acc1 * acc1;
    __syncthreads();
    for (int s = 128; s > 0; s >>= 1) {
        if (tid < s) red[tid] += red[tid + s];
        __syncthreads();
    }
    float Q = red[0];
    float mean = S * (1.f / DIM);
    float var = Q * (1.f / DIM) - mean * mean;
    float rs2 = rsqrtf(var + 1e-5f);
    trow[tid]       = (acc0 - mean) * rs2 * pln2_g[e * DIM + tid]       + pln2_b[e * DIM + tid]       + pe[tid];
    trow[tid + 256] = (acc1 - mean) * rs2 * pln2_g[e * DIM + tid + 256] + pln2_b[e * DIM + tid + 256] + pe[tid + 256];
}

// ---------------------------------------------------------------------------
// LayerNorm over gathered rows: fp32 t (linear) -> bf16 dst (st8-SWIZZLED).
// ---------------------------------------------------------------------------
__global__ __launch_bounds__(256) void ln2_k(const float* __restrict__ src,
                                             u16* __restrict__ dst,
                                             const float* __restrict__ gbase,
                                             const float* __restrict__ bbase,
                                             const int* __restrict__ tile_e,
                                             int gestride) {
    int row = blockIdx.x * 4 + (threadIdx.x >> 6);
    int lane = threadIdx.x & 63;
    int e = tile_e[row >> 8];
    if (e < 0) return;
    const float* s = src + (size_t)row * 512;
    float4 a = *(const float4*)&s[lane * 4];
    float4 b = *(const float4*)&s[256 + lane * 4];
    float sum = a.x + a.y + a.z + a.w + b.x + b.y + b.z + b.w;
    float sq = a.x * a.x + a.y * a.y + a.z * a.z + a.w * a.w +
               b.x * b.x + b.y * b.y + b.z * b.z + b.w * b.w;
#pragma unroll
    for (int off = 32; off > 0; off >>= 1) {
        sum += __shfl_xor(sum, off);
        sq += __shfl_xor(sq, off);
    }
    float mean = sum * (1.f / DIM);
    float rs = rsqrtf(sq * (1.f / DIM) - mean * mean + 1e-5f);
    const float* g = gbase + (size_t)e * gestride;
    const float* bb = bbase + (size_t)e * gestride;
    float4 g0 = *(const float4*)&g[lane * 4];
    float4 g1 = *(const float4*)&g[256 + lane * 4];
    float4 b0 = *(const float4*)&bb[lane * 4];
    float4 b1 = *(const float4*)&bb[256 + lane * 4];
    int swz = (row & 7) << 3;
    u16 o[4];
    o[0] = f2bf((a.x - mean) * rs * g0.x + b0.x);
    o[1] = f2bf((a.y - mean) * rs * g0.y + b0.y);
    o[2] = f2bf((a.z - mean) * rs * g0.z + b0.z);
    o[3] = f2bf((a.w - mean) * rs * g0.w + b0.w);
    *(int2*)&dst[(size_t)row * 512 + ((lane * 4) ^ swz)] = *(int2*)o;
    o[0] = f2bf((b.x - mean) * rs * g1.x + b1.x);
    o[1] = f2bf((b.y - mean) * rs * g1.y + b1.y);
    o[2] = f2bf((b.z - mean) * rs * g1.z + b1.z);
    o[3] = f2bf((b.w - mean) * rs * g1.w + b1.w);
    *(int2*)&dst[(size_t)row * 512 + ((256 + lane * 4) ^ swz)] = *(int2*)o;
}

// ---------------------------------------------------------------------------
// Weight convert fp32 [512][N] -> bf16 [N][512] transposed + st8-swizzled.
// ---------------------------------------------------------------------------
__device__ inline void wconv_body(const float* __restrict__ s,
                                  u16* __restrict__ d, int N,
                                  int n0, int k0, int tid) {
    __shared__ float tile[32][33];
    int r = tid >> 5, c = tid & 31;
#pragma unroll
    for (int i = 0; i < 4; ++i)
        tile[r + i * 8][c] = s[(size_t)(k0 + r + i * 8) * N + n0 + c];
    __syncthreads();
#pragma unroll
    for (int i = 0; i < 4; ++i) {
        int n = n0 + r + i * 8;
        d[(size_t)n * 512 + ((k0 + c) ^ ((n & 7) << 3))] = f2bf(tile[c][r + i * 8]);
    }
}

__global__ __launch_bounds__(256) void wconv_k(const float* __restrict__ src,
                                               u16* __restrict__ dst, int N) {
    wconv_body(src + (size_t)blockIdx.z * 512 * N, dst + (size_t)blockIdx.z * 512 * N,
               N, blockIdx.x * 32, blockIdx.y * 32, threadIdx.x);
}

// one launch for the three 512-wide weight sets; grid (16,16,144)
__global__ __launch_bounds__(256) void wconv3_k(const float* __restrict__ s0,
                                                const float* __restrict__ s1,
                                                const float* __restrict__ s2,
                                                u16* __restrict__ d0,
                                                u16* __restrict__ d1,
                                                u16* __restrict__ d2) {
    int z = blockIdx.z, which = z / 48, m = z % 48;
    const float* s = (which == 0) ? s0 : (which == 1) ? s1 : s2;
    u16* d = (which == 0) ? d0 : (which == 1) ? d1 : d2;
    wconv_body(s + (size_t)m * 512 * 512, d + (size_t)m * 512 * 512,
               512, blockIdx.x * 32, blockIdx.y * 32, threadIdx.x);
}

// ---------------------------------------------------------------------------
// Generic batched MFMA GEMM, double-buffered LDS + counted vmcnt (T3/T4-lite).
// Block = (MW*32) rows x 128 cols, 4 waves (2x2), wave tile = (MW*16) x 64.
//   MW=4 -> 128x128 (qkv, grid 960, LDS 64KB); MW=2 -> 64x128 (grid 640, 48KB).
// Per k-step: issue next tile's global_load_lds into buf^1, then
// s_waitcnt vmcnt(LOADS) (waits only the PREVIOUS tile's loads) + raw barrier.
// OP: 0 = store bf16 linear; 1 = fp32 t += acc+bias; 2 = bias+GELU -> SWZ bf16
// ---------------------------------------------------------------------------
template <int N, int OP, int MW>
__global__ __launch_bounds__(256) void mgemm_k(const u16* __restrict__ A,
                                               const u16* __restrict__ Wtbase,
                                               const float* __restrict__ Bbase,
                                               void* __restrict__ Cptr,
                                               const int* __restrict__ tile_e,
                                               int westride, int bestride) {
    constexpr int M = MW * 32;
    constexpr int CT = N / 128;
    constexpr int MTILES = NROWSP / M;
    constexpr int ALOADS = M / 32;          // per-wave A loads per tile
    constexpr int LOADS = ALOADS + 4;       // per-wave total loads per tile
    int orig = blockIdx.x, nwg = MTILES * CT;
    int q = nwg >> 3, r8 = nwg & 7;
    int xcd = orig & 7, off = orig >> 3;
    int wg = (xcd < r8 ? xcd * (q + 1) : r8 * (q + 1) + (xcd - r8) * q) + off;
    int tile = wg / CT, ct = wg - tile * CT;
    int e = tile_e[(tile * M) >> 8];
    if (e < 0) return;
    int row0 = tile * M, c0 = ct * 128;
    const u16* Wt = Wtbase + (size_t)e * westride;

    int tid = threadIdx.x;
    int lane = tid & 63, w = tid >> 6;
    int rl = lane & 15, kg = lane >> 4;
    int wr = w >> 1, wc = w & 1;

    __shared__ __align__(16) u16 As[2][M * 64];
    __shared__ __align__(16) u16 Bs[2][128 * 64];

    f32x4 acc[MW][4];
#pragma unroll
    for (int mt = 0; mt < MW; ++mt)
#pragma unroll
        for (int nt = 0; nt < 4; ++nt) acc[mt][nt] = (f32x4){0.f, 0.f, 0.f, 0.f};

    const u16* Ag = A + (size_t)(row0 + w * (M / 4) + (lane >> 3)) * 512 + (lane & 7) * 8;
    const u16* Bg = Wt + (size_t)(c0 + w * 32 + (lane >> 3)) * 512 + (lane & 7) * 8;
    int aoff = w * (M / 4) * 64;   // wave-uniform LDS dest offsets
    int boff = w * 2048;

    int blk0 = (kg ^ (rl & 7)) * 8;
    int blk1 = ((4 + kg) ^ (rl & 7)) * 8;

    // prologue: tile 0 into buf 0
#pragma unroll
    for (int i = 0; i < ALOADS; ++i)
        GLOAD_LDS16(Ag + i * 8 * 512, &As[0][aoff + i * 512]);
#pragma unroll
    for (int i = 0; i < 4; ++i)
        GLOAD_LDS16(Bg + i * 8 * 512, &Bs[0][boff + i * 512]);

    for (int it = 0; it < 8; ++it) {
        int cur = it & 1;
        if (it < 7) {
            int kk = (it + 1) * 64;
            int nxt = cur ^ 1;
#pragma unroll
            for (int i = 0; i < ALOADS; ++i)
                GLOAD_LDS16(Ag + kk + i * 8 * 512, &As[nxt][aoff + i * 512]);
#pragma unroll
            for (int i = 0; i < 4; ++i)
                GLOAD_LDS16(Bg + kk + i * 8 * 512, &Bs[nxt][boff + i * 512]);
            asm volatile("s_waitcnt vmcnt(%0)" :: "n"(LOADS) : "memory");
        } else {
            asm volatile("s_waitcnt vmcnt(0)" ::: "memory");
        }
        __builtin_amdgcn_s_barrier();
        asm volatile("" ::: "memory");
#pragma unroll
        for (int ks = 0; ks < 2; ++ks) {
            int blk = ks ? blk1 : blk0;
            bf16x8 av[MW], bv[4];
#pragma unroll
            for (int i = 0; i < MW; ++i)
                av[i] = *(const bf16x8*)&As[cur][(wr * (M / 2) + i * 16 + rl) * 64 + blk];
#pragma unroll
            for (int i = 0; i < 4; ++i)
                bv[i] = *(const bf16x8*)&Bs[cur][(wc * 64 + i * 16 + rl) * 64 + blk];
#pragma unroll
            for (int mt = 0; mt < MW; ++mt)
#pragma unroll
                for (int nt = 0; nt < 4; ++nt)
                    acc[mt][nt] = __builtin_amdgcn_mfma_f32_16x16x32_bf16(
                        av[mt], bv[nt], acc[mt][nt], 0, 0, 0);
        }
        asm volatile("" ::: "memory");
        __builtin_amdgcn_s_barrier();   // all waves done reading buf before reuse
    }

    int rh = lane >> 4;
#pragma unroll
    for (int mt = 0; mt < MW; ++mt)
#pragma unroll
        for (int nt = 0; nt < 4; ++nt)
#pragma unroll
            for (int rr = 0; rr < 4; ++rr) {
                size_t grow = row0 + wr * (M / 2) + mt * 16 + rh * 4 + rr;
                int c = c0 + wc * 64 + nt * 16 + rl;
                float v = acc[mt][nt][rr];
                if (OP == 0) {
                    ((u16*)Cptr)[grow * N + c] = f2bf(v);
                } else if (OP == 1) {
                    ((float*)Cptr)[grow * 512 + c] += v + Bbase[(size_t)e * bestride + c];
                } else {
                    float vb = v + Bbase[(size_t)e * bestride + c];
                    float gl = vb * 0.5f * (1.f + erff(vb * 0.70710678118f));
                    ((u16*)Cptr)[grow * 512 + (c ^ (((int)grow & 7) << 3))] = f2bf(gl);
                }
            }
}

// ---------------------------------------------------------------------------
// MFMA attention: 1-D grid 1024 (b-major). 5 waves, wave w owns m-tile w.
// qkv (linear) in, out st8-SWIZZLED.
// ---------------------------------------------------------------------------
#define ATT_LDS (23040 / 2 + 8320 / 2 + 12288 / 2)
__global__ __launch_bounds__(320) void attn3_k(const u16* __restrict__ qkv,
                                               u16* __restrict__ o,
                                               const int* __restrict__ prow) {
    int b = blockIdx.x & 127, h = blockIdx.x >> 7, tid = threadIdx.x;
    int pr = prow[b];
    __shared__ __align__(16) u16 smem[ATT_LDS];
    u16* Qs = smem;                    // [80][72]
    u16* Ks = smem + 80 * 72;          // [80][72]
    u16* Ps = smem;                    // [80][96]
    u16* Vs = smem + 2 * 80 * 72;      // [65][64]
    u16* Vt = Vs + 65 * 64;            // [64][96]

    const u16* base = qkv + (size_t)pr * 1536 + h * 64;

    for (int idx = tid; idx < 640; idx += 320) {
        int r = idx >> 3, q = idx & 7;
        int4 vq = {0, 0, 0, 0}, vk = {0, 0, 0, 0};
        if (r < NTOK) {
            vq = *(const int4*)&base[(size_t)r * 1536 + q * 8];
            vk = *(const int4*)&base[(size_t)r * 1536 + 512 + q * 8];
        }
        *(int4*)&Qs[r * 72 + q * 8] = vq;
        *(int4*)&Ks[r * 72 + q * 8] = vk;
    }
    for (int idx = tid; idx < 520; idx += 320) {
        int r = idx >> 3, q = idx & 7;
        *(int4*)&Vs[r * 64 + q * 8] = *(const int4*)&base[(size_t)r * 1536 + 1024 + q * 8];
    }
    __syncthreads();

    int lane = tid & 63, mt = tid >> 6;
    int rl = lane & 15, kg = lane >> 4, g = lane >> 4;

    f32x4 acc[5];
#pragma unroll
    for (int nt = 0; nt < 5; ++nt) acc[nt] = (f32x4){0.f, 0.f, 0.f, 0.f};

    {
        bf16x8 av0 = *(const bf16x8*)&Qs[(mt * 16 + rl) * 72 + kg * 8];
        bf16x8 av1 = *(const bf16x8*)&Qs[(mt * 16 + rl) * 72 + 32 + kg * 8];
#pragma unroll
        for (int nt = 0; nt < 5; ++nt) {
            bf16x8 bv0 = *(const bf16x8*)&Ks[(nt * 16 + rl) * 72 + kg * 8];
            bf16x8 bv1 = *(const bf16x8*)&Ks[(nt * 16 + rl) * 72 + 32 + kg * 8];
            acc[nt] = __builtin_amdgcn_mfma_f32_16x16x32_bf16(av0, bv0, acc[nt], 0, 0, 0);
            acc[nt] = __builtin_amdgcn_mfma_f32_16x16x32_bf16(av1, bv1, acc[nt], 0, 0, 0);
        }
    }

    for (int idx = tid; idx < 768; idx += 320) {
        int d = idx & 63, kq = idx >> 6;
        u16 tmp[8];
#pragma unroll
        for (int j = 0; j < 8; ++j) {
            int k = kq * 8 + j;
            tmp[j] = (k < NTOK) ? Vs[k * 64 + d] : (u16)0;
        }
        *(int4*)&Vt[d * 96 + kq * 8] = *(int4*)tmp;
    }

#pragma unroll
    for (int r = 0; r < 4; ++r) {
        float m = -3.0e38f;
#pragma unroll
        for (int nt = 0; nt < 5; ++nt) {
            float s = acc[nt][r] * 0.125f;
            if (nt * 16 + rl >= NTOK) s = -3.0e38f;
            acc[nt][r] = s;
            m = fmaxf(m, s);
        }
        m = fmaxf(m, __shfl_xor(m, 1));
        m = fmaxf(m, __shfl_xor(m, 2));
        m = fmaxf(m, __shfl_xor(m, 4));
        m = fmaxf(m, __shfl_xor(m, 8));
        float sum = 0.f;
#pragma unroll
        for (int nt = 0; nt < 5; ++nt) {
            float p = expf(acc[nt][r] - m);
            acc[nt][r] = p;
            sum += p;
        }
        sum += __shfl_xor(sum, 1);
        sum += __shfl_xor(sum, 2);
        sum += __shfl_xor(sum, 4);
        sum += __shfl_xor(sum, 8);
        float inv = 1.f / sum;
#pragma unroll
        for (int nt = 0; nt < 5; ++nt) acc[nt][r] *= inv;
    }
    __syncthreads();

#pragma unroll
    for (int nt = 0; nt < 5; ++nt)
#pragma unroll
        for (int r = 0; r < 4; ++r)
            Ps[(mt * 16 + g * 4 + r) * 96 + nt * 16 + rl] = f2bf(acc[nt][r]);
    for (int idx = tid; idx < 160; idx += 320) {
        int r = idx >> 1, hf = idx & 1;
        *(int4*)&Ps[r * 96 + 80 + hf * 8] = (int4){0, 0, 0, 0};
    }
    __syncthreads();

#pragma unroll
    for (int dt = 0; dt < 4; ++dt) {
        f32x4 oa = {0.f, 0.f, 0.f, 0.f};
#pragma unroll
        for (int s2 = 0; s2 < 3; ++s2) {
            bf16x8 av = *(const bf16x8*)&Ps[(mt * 16 + rl) * 96 + s2 * 32 + kg * 8];
            bf16x8 bv = *(const bf16x8*)&Vt[(dt * 16 + rl) * 96 + s2 * 32 + kg * 8];
            oa = __builtin_amdgcn_mfma_f32_16x16x32_bf16(av, bv, oa, 0, 0, 0);
        }
#pragma unroll
        for (int r = 0; r < 4; ++r) {
            int row = mt * 16 + g * 4 + r;
            if (row < NTOK) {
                int grow = pr + row;
                int c = h * 64 + dt * 16 + rl;
                o[(size_t)grow * DIM + (c ^ ((grow & 7) << 3))] = f2bf(oa[r]);
            }
        }
    }
}

// ---------------------------------------------------------------------------
// Final LN (token 0) + head (fp32)
// ---------------------------------------------------------------------------
__global__ __launch_bounds__(64) void final_k(const float* __restrict__ t,
                                              const float* __restrict__ fg,
                                              const float* __restrict__ fb,
                                              const float* __restrict__ hw,
                                              const float* __restrict__ hb,
                                              const int* __restrict__ top1,
                                              const int* __restrict__ prow,
                                              float* __restrict__ out) {
    int b = blockIdx.x, lane = threadIdx.x;
    int e = top1[b];
    const float* row = t + (size_t)prow[b] * DIM;
    float v[8], s = 0.f, q = 0.f;
#pragma unroll
    for (int ii = 0; ii < 8; ++ii) {
        v[ii] = row[ii * 64 + lane];
        s += v[ii];
        q += v[ii] * v[ii];
    }
    for (int off = 32; off > 0; off >>= 1) {
        s += __shfl_xor(s, off);
        q += __shfl_xor(q, off);
    }
    float mean = s * (1.f / DIM);
    float var = q * (1.f / DIM) - mean * mean;
    float rs = rsqrtf(var + 1e-5f);
    float nv[8];
#pragma unroll
    for (int ii = 0; ii < 8; ++ii) {
        int d = ii * 64 + lane;
        nv[ii] = (v[ii] - mean) * rs * fg[e * DIM + d] + fb[e * DIM + d];
    }
    for (int c = 0; c < NCLS; ++c) {
        float p = 0.f;
#pragma unroll
        for (int ii = 0; ii < 8; ++ii) {
            int d = ii * 64 + lane;
            p = fmaf(nv[ii], hw[(size_t)e * DIM * NCLS + d * NCLS + c], p);
        }
        for (int off = 32; off > 0; off >>= 1) p += __shfl_xor(p, off);
        if (lane == 0) out[b * NCLS + c] = p + hb[e * NCLS + c];
    }
}

// ---------------------------------------------------------------------------
extern "C" void kernel_launch(void* const* d_in, const int* in_sizes, int n_in,
                              void* d_out, int out_size, void* d_ws, size_t ws_size,
                              hipStream_t stream) {
    const float* x       = (const float*)d_in[0];
    const float* gate_w  = (const float*)d_in[1];
    const float* gate_b  = (const float*)d_in[2];
    const float* pln1_g  = (const float*)d_in[3];
    const float* pln1_b  = (const float*)d_in[4];
    const float* patch_w = (const float*)d_in[5];
    const float* patch_b = (const float*)d_in[6];
    const float* pln2_g  = (const float*)d_in[7];
    const float* pln2_b  = (const float*)d_in[8];
    const float* cls_tok = (const float*)d_in[9];
    const float* pos_emb = (const float*)d_in[10];
    const float* aln_g   = (const float*)d_in[11];
    const float* aln_b   = (const float*)d_in[12];
    const float* qkv_w   = (const float*)d_in[13];
    const float* out_w   = (const float*)d_in[14];
    const float* out_b   = (const float*)d_in[15];
    const float* fln_g   = (const float*)d_in[16];
    const float* fln_b   = (const float*)d_in[17];
    const float* ff1_w   = (const float*)d_in[18];
    const float* ff1_b   = (const float*)d_in[19];
    const float* ff2_w   = (const float*)d_in[20];
    const float* ff2_b   = (const float*)d_in[21];
    const float* final_g = (const float*)d_in[22];
    const float* final_b = (const float*)d_in[23];
    const float* head_w  = (const float*)d_in[24];
    const float* head_b  = (const float*)d_in[25];
    float* out = (float*)d_out;

    // Workspace (~260 MB of ~600 MB)
    int* top1   = (int*)d_ws;                                // 128
    int* prow   = top1 + 128;                                // 128
    int* tile_e = prow + 128;                                // 40 (pad)
    float* t  = (float*)((char*)d_ws + 4096);                // fp32 [NROWSP][512] linear
    u16* aln  = (u16*)(t + (size_t)NROWSP * DIM);            // bf16 [NROWSP][512] SWZ
    u16* qb16 = aln + (size_t)NROWSP * DIM;                  // bf16 [NROWSP][1536] linear
    u16* ao16 = qb16 + (size_t)NROWSP * 1536;                // bf16 [NROWSP][512] SWZ
    u16* h16  = ao16 + (size_t)NROWSP * DIM;                 // bf16 [NROWSP][512] SWZ
    u16* wq_t = h16 + (size_t)NROWSP * DIM;                  // bf16 [48][1536][512] SWZ
    u16* wo_t = wq_t + (size_t)48 * 1536 * 512;              // bf16 [48][512][512] SWZ
    u16* w1_t = wo_t + (size_t)48 * 512 * 512;
    u16* w2_t = w1_t + (size_t)48 * 512 * 512;

    gate_k<<<BATCH, 256, 0, stream>>>(x, gate_w, gate_b, top1);
    route3_k<<<1, 128, 0, stream>>>(top1, prow, tile_e);
    patch_k<<<dim3(NTOK, BATCH), 256, 0, stream>>>(x, pln1_g, pln1_b, patch_w, patch_b,
                                                   pln2_g, pln2_b, cls_tok, pos_emb,
                                                   top1, prow, t);
    wconv_k<<<dim3(48, 16, 48), 256, 0, stream>>>(qkv_w, wq_t, 1536);
    wconv3_k<<<dim3(16, 16, 144), 256, 0, stream>>>(out_w, ff1_w, ff2_w, wo_t, w1_t, w2_t);

    for (int l = 0; l < DEPTH; ++l) {
        ln2_k<<<NROWSP / 4, 256, 0, stream>>>(t, aln, aln_g + l * DIM, aln_b + l * DIM,
                                              tile_e, DEPTH * DIM);
        mgemm_k<1536, 0, 4><<<(NROWSP / 128) * 12, 256, 0, stream>>>(
            aln, wq_t + (size_t)l * 1536 * 512, nullptr, qb16, tile_e,
            DEPTH * 512 * 1536, 0);
        attn3_k<<<HEADS * BATCH, 320, 0, stream>>>(qb16, ao16, prow);
        mgemm_k<512, 1, 2><<<(NROWSP / 64) * 4, 256, 0, stream>>>(
            ao16, wo_t + (size_t)l * 512 * 512, out_b + l * DIM, t, tile_e,
            DEPTH * 512 * 512, DEPTH * DIM);
        ln2_k<<<NROWSP / 4, 256, 0, stream>>>(t, aln, fln_g + l * DIM, fln_b + l * DIM,
                                              tile_e, DEPTH * DIM);
        mgemm_k<512, 2, 2><<<(NROWSP / 64) * 4, 256, 0, stream>>>(
            aln, w1_t + (size_t)l * 512 * 512, ff1_b + l * DIM, h16, tile_e,
            DEPTH * 512 * 512, DEPTH * DIM);
        mgemm_k<512, 1, 2><<<(NROWSP / 64) * 4, 256, 0, stream>>>(
            h16, w2_t + (size_t)l * 512 * 512, ff2_b + l * DIM, t, tile_e,
            DEPTH * 512 * 512, DEPTH * DIM);
    }
    final_k<<<BATCH, 64, 0, stream>>>(t, final_g, final_b, head_w, head_b, top1, prow, out);
}

// Round 14
// 801.878 us; speedup vs baseline: 1.3712x; 1.0001x over previous
//
#include <hip/hip_runtime.h>
#include <math.h>

#define EXPERTS 8
#define DEPTH 6
#define DIM 512
#define HEADS 8
#define NCLS 10
#define BATCH 128
#define PD 48
#define NTOK 65
#define NRT256 40              // max 256-row tiles
#define NROWSP (NRT256 * 256)  // 10240 gathered rows

typedef __attribute__((ext_vector_type(4))) float f32x4;
typedef __attribute__((ext_vector_type(8))) __bf16 bf16x8;
typedef unsigned short u16;

#define GLOAD_LDS16(gp, lp)                                                     \
    __builtin_amdgcn_global_load_lds(                                           \
        (const __attribute__((address_space(1))) void*)(gp),                    \
        (__attribute__((address_space(3))) void*)(lp), 16, 0, 0)

__device__ inline u16 f2bf(float f) {
    union { float f; unsigned u; } v; v.f = f;
    unsigned r = v.u + 0x7FFFu + ((v.u >> 16) & 1u);
    return (u16)(r >> 16);
}

// ---------------------------------------------------------------------------
// Gate (exact fp32 — routing must not flip)
// ---------------------------------------------------------------------------
__global__ __launch_bounds__(256) void gate_k(const float* __restrict__ x,
                                              const float* __restrict__ gw,
                                              const float* __restrict__ gb,
                                              int* __restrict__ top1) {
    int b = blockIdx.x, tid = threadIdx.x;
    const float* xb = x + (size_t)b * 3072;
    float acc[EXPERTS];
#pragma unroll
    for (int e = 0; e < EXPERTS; ++e) acc[e] = 0.f;
    for (int i = tid; i < 3072; i += 256) {
        float xv = xb[i];
#pragma unroll
        for (int e = 0; e < EXPERTS; ++e)
            acc[e] = fmaf(xv, gw[(size_t)e * 3072 + i], acc[e]);
    }
    __shared__ float red[256];
    __shared__ float logits[EXPERTS];
    for (int e = 0; e < EXPERTS; ++e) {
        red[tid] = acc[e];
        __syncthreads();
        for (int s = 128; s > 0; s >>= 1) {
            if (tid < s) red[tid] += red[tid + s];
            __syncthreads();
        }
        if (tid == 0) logits[e] = red[0] + gb[e];
        __syncthreads();
    }
    if (tid == 0) {
        int best = 0;
        float bv = logits[0];
        for (int e = 1; e < EXPERTS; ++e)
            if (logits[e] > bv) { bv = logits[e]; best = e; }
        top1[b] = best;
    }
}

// ---------------------------------------------------------------------------
// Routing: gathered rows, experts padded to 256-row tiles.
// ---------------------------------------------------------------------------
__global__ __launch_bounds__(128) void route3_k(const int* __restrict__ top1,
                                                int* __restrict__ prow,
                                                int* __restrict__ tile_e) {
    __shared__ int t1[BATCH];
    int tid = threadIdx.x;
    t1[tid] = top1[tid];
    __syncthreads();
    if (tid != 0) return;
    int row = 0, tile = 0;
    for (int e = 0; e < EXPERTS; ++e) {
        int ne = 0;
        for (int b = 0; b < BATCH; ++b)
            if (t1[b] == e) { prow[b] = row + ne * 65; ne++; }
        if (!ne) continue;
        int nt = (ne * 65 + 255) >> 8;
        for (int tt = 0; tt < nt; ++tt) tile_e[tile++] = e;
        row += nt << 8;
    }
    for (; tile < NRT256; ++tile) tile_e[tile] = -1;
}

// ---------------------------------------------------------------------------
// Patch embed (fp32, writes gathered residual stream t, linear)
// ---------------------------------------------------------------------------
__global__ __launch_bounds__(256) void patch_k(const float* __restrict__ x,
                                               const float* __restrict__ pln1_g,
                                               const float* __restrict__ pln1_b,
                                               const float* __restrict__ patch_w,
                                               const float* __restrict__ patch_b,
                                               const float* __restrict__ pln2_g,
                                               const float* __restrict__ pln2_b,
                                               const float* __restrict__ cls_tok,
                                               const float* __restrict__ pos_emb,
                                               const int* __restrict__ top1,
                                               const int* __restrict__ prow,
                                               float* __restrict__ t) {
    int n = blockIdx.x, b = blockIdx.y, tid = threadIdx.x;
    int e = top1[b];
    float* trow = t + ((size_t)prow[b] + n) * DIM;
    const float* pe = pos_emb + ((size_t)e * NTOK + n) * DIM;

    if (n == 0) {
        for (int d = tid; d < DIM; d += 256)
            trow[d] = cls_tok[e * DIM + d] + pe[d];
        return;
    }
    int pi = n - 1, h = pi >> 3, w = pi & 7;
    __shared__ float pv[PD];
    __shared__ float red[256];
    if (tid < PD) {
        int p1 = tid / 12, rem = tid % 12, p2 = rem / 3, c = rem % 3;
        pv[tid] = x[((size_t)b * 3 + c) * 1024 + (h * 4 + p1) * 32 + (w * 4 + p2)];
    }
    __syncthreads();
    float m = 0.f, q = 0.f;
    for (int j = 0; j < PD; ++j) { float v = pv[j]; m += v; q += v * v; }
    m *= (1.f / PD);
    q = q * (1.f / PD) - m * m;
    float rs = rsqrtf(q + 1e-5f);
    __syncthreads();
    if (tid < PD)
        pv[tid] = (pv[tid] - m) * rs * pln1_g[e * PD + tid] + pln1_b[e * PD + tid];
    __syncthreads();

    float acc0 = patch_b[e * DIM + tid];
    float acc1 = patch_b[e * DIM + tid + 256];
    for (int j = 0; j < PD; ++j) {
        float v = pv[j];
        const float* wr = patch_w + ((size_t)e * PD + j) * DIM;
        acc0 = fmaf(v, wr[tid], acc0);
        acc1 = fmaf(v, wr[tid + 256], acc1);
    }
    red[tid] = acc0 + acc1;
    __syncthreads();
    for (int s = 128; s > 0; s >>= 1) {
        if (tid < s) red[tid] += red[tid + s];
        __syncthreads();
    }
    float S = red[0];
    __syncthreads();
    red[tid] = acc0 * acc0 + acc1 * acc1;
    __syncthreads();
    for (int s = 128; s > 0; s >>= 1) {
        if (tid < s) red[tid] += red[tid + s];
        __syncthreads();
    }
    float Q = red[0];
    float mean = S * (1.f / DIM);
    float var = Q * (1.f / DIM) - mean * mean;
    float rs2 = rsqrtf(var + 1e-5f);
    trow[tid]       = (acc0 - mean) * rs2 * pln2_g[e * DIM + tid]       + pln2_b[e * DIM + tid]       + pe[tid];
    trow[tid + 256] = (acc1 - mean) * rs2 * pln2_g[e * DIM + tid + 256] + pln2_b[e * DIM + tid + 256] + pe[tid + 256];
}

// ---------------------------------------------------------------------------
// LayerNorm over gathered rows: fp32 t (linear) -> bf16 dst (st8-SWIZZLED).
// ---------------------------------------------------------------------------
__global__ __launch_bounds__(256) void ln2_k(const float* __restrict__ src,
                                             u16* __restrict__ dst,
                                             const float* __restrict__ gbase,
                                             const float* __restrict__ bbase,
                                             const int* __restrict__ tile_e,
                                             int gestride) {
    int row = blockIdx.x * 4 + (threadIdx.x >> 6);
    int lane = threadIdx.x & 63;
    int e = tile_e[row >> 8];
    if (e < 0) return;
    const float* s = src + (size_t)row * 512;
    float4 a = *(const float4*)&s[lane * 4];
    float4 b = *(const float4*)&s[256 + lane * 4];
    float sum = a.x + a.y + a.z + a.w + b.x + b.y + b.z + b.w;
    float sq = a.x * a.x + a.y * a.y + a.z * a.z + a.w * a.w +
               b.x * b.x + b.y * b.y + b.z * b.z + b.w * b.w;
#pragma unroll
    for (int off = 32; off > 0; off >>= 1) {
        sum += __shfl_xor(sum, off);
        sq += __shfl_xor(sq, off);
    }
    float mean = sum * (1.f / DIM);
    float rs = rsqrtf(sq * (1.f / DIM) - mean * mean + 1e-5f);
    const float* g = gbase + (size_t)e * gestride;
    const float* bb = bbase + (size_t)e * gestride;
    float4 g0 = *(const float4*)&g[lane * 4];
    float4 g1 = *(const float4*)&g[256 + lane * 4];
    float4 b0 = *(const float4*)&bb[lane * 4];
    float4 b1 = *(const float4*)&bb[256 + lane * 4];
    int swz = (row & 7) << 3;
    u16 o[4];
    o[0] = f2bf((a.x - mean) * rs * g0.x + b0.x);
    o[1] = f2bf((a.y - mean) * rs * g0.y + b0.y);
    o[2] = f2bf((a.z - mean) * rs * g0.z + b0.z);
    o[3] = f2bf((a.w - mean) * rs * g0.w + b0.w);
    *(int2*)&dst[(size_t)row * 512 + ((lane * 4) ^ swz)] = *(int2*)o;
    o[0] = f2bf((b.x - mean) * rs * g1.x + b1.x);
    o[1] = f2bf((b.y - mean) * rs * g1.y + b1.y);
    o[2] = f2bf((b.z - mean) * rs * g1.z + b1.z);
    o[3] = f2bf((b.w - mean) * rs * g1.w + b1.w);
    *(int2*)&dst[(size_t)row * 512 + ((256 + lane * 4) ^ swz)] = *(int2*)o;
}

// ---------------------------------------------------------------------------
// Weight convert fp32 [512][N] -> bf16 [N][512] transposed + st8-swizzled.
// ---------------------------------------------------------------------------
__device__ inline void wconv_body(const float* __restrict__ s,
                                  u16* __restrict__ d, int N,
                                  int n0, int k0, int tid) {
    __shared__ float tile[32][33];
    int r = tid >> 5, c = tid & 31;
#pragma unroll
    for (int i = 0; i < 4; ++i)
        tile[r + i * 8][c] = s[(size_t)(k0 + r + i * 8) * N + n0 + c];
    __syncthreads();
#pragma unroll
    for (int i = 0; i < 4; ++i) {
        int n = n0 + r + i * 8;
        d[(size_t)n * 512 + ((k0 + c) ^ ((n & 7) << 3))] = f2bf(tile[c][r + i * 8]);
    }
}

__global__ __launch_bounds__(256) void wconv_k(const float* __restrict__ src,
                                               u16* __restrict__ dst, int N) {
    wconv_body(src + (size_t)blockIdx.z * 512 * N, dst + (size_t)blockIdx.z * 512 * N,
               N, blockIdx.x * 32, blockIdx.y * 32, threadIdx.x);
}

// one launch for the three 512-wide weight sets; grid (16,16,144)
__global__ __launch_bounds__(256) void wconv3_k(const float* __restrict__ s0,
                                                const float* __restrict__ s1,
                                                const float* __restrict__ s2,
                                                u16* __restrict__ d0,
                                                u16* __restrict__ d1,
                                                u16* __restrict__ d2) {
    int z = blockIdx.z, which = z / 48, m = z % 48;
    const float* s = (which == 0) ? s0 : (which == 1) ? s1 : s2;
    u16* d = (which == 0) ? d0 : (which == 1) ? d1 : d2;
    wconv_body(s + (size_t)m * 512 * 512, d + (size_t)m * 512 * 512,
               512, blockIdx.x * 32, blockIdx.y * 32, threadIdx.x);
}

// ---------------------------------------------------------------------------
// Generic batched MFMA GEMM, double-buffered LDS + counted vmcnt.
// OP: 0 = store bf16 SEG-SWIZZLED (qkv -> qb16, per-64-col st8 XOR);
//     1 = fp32 t += acc+bias; 2 = bias+GELU -> SWZ bf16
// ---------------------------------------------------------------------------
template <int N, int OP, int MW>
__global__ __launch_bounds__(256) void mgemm_k(const u16* __restrict__ A,
                                               const u16* __restrict__ Wtbase,
                                               const float* __restrict__ Bbase,
                                               void* __restrict__ Cptr,
                                               const int* __restrict__ tile_e,
                                               int westride, int bestride) {
    constexpr int M = MW * 32;
    constexpr int CT = N / 128;
    constexpr int MTILES = NROWSP / M;
    constexpr int ALOADS = M / 32;
    constexpr int LOADS = ALOADS + 4;
    int orig = blockIdx.x, nwg = MTILES * CT;
    int q = nwg >> 3, r8 = nwg & 7;
    int xcd = orig & 7, off = orig >> 3;
    int wg = (xcd < r8 ? xcd * (q + 1) : r8 * (q + 1) + (xcd - r8) * q) + off;
    int tile = wg / CT, ct = wg - tile * CT;
    int e = tile_e[(tile * M) >> 8];
    if (e < 0) return;
    int row0 = tile * M, c0 = ct * 128;
    const u16* Wt = Wtbase + (size_t)e * westride;

    int tid = threadIdx.x;
    int lane = tid & 63, w = tid >> 6;
    int rl = lane & 15, kg = lane >> 4;
    int wr = w >> 1, wc = w & 1;

    __shared__ __align__(16) u16 As[2][M * 64];
    __shared__ __align__(16) u16 Bs[2][128 * 64];

    f32x4 acc[MW][4];
#pragma unroll
    for (int mt = 0; mt < MW; ++mt)
#pragma unroll
        for (int nt = 0; nt < 4; ++nt) acc[mt][nt] = (f32x4){0.f, 0.f, 0.f, 0.f};

    const u16* Ag = A + (size_t)(row0 + w * (M / 4) + (lane >> 3)) * 512 + (lane & 7) * 8;
    const u16* Bg = Wt + (size_t)(c0 + w * 32 + (lane >> 3)) * 512 + (lane & 7) * 8;
    int aoff = w * (M / 4) * 64;
    int boff = w * 2048;

    int blk0 = (kg ^ (rl & 7)) * 8;
    int blk1 = ((4 + kg) ^ (rl & 7)) * 8;

#pragma unroll
    for (int i = 0; i < ALOADS; ++i)
        GLOAD_LDS16(Ag + i * 8 * 512, &As[0][aoff + i * 512]);
#pragma unroll
    for (int i = 0; i < 4; ++i)
        GLOAD_LDS16(Bg + i * 8 * 512, &Bs[0][boff + i * 512]);

    for (int it = 0; it < 8; ++it) {
        int cur = it & 1;
        if (it < 7) {
            int kk = (it + 1) * 64;
            int nxt = cur ^ 1;
#pragma unroll
            for (int i = 0; i < ALOADS; ++i)
                GLOAD_LDS16(Ag + kk + i * 8 * 512, &As[nxt][aoff + i * 512]);
#pragma unroll
            for (int i = 0; i < 4; ++i)
                GLOAD_LDS16(Bg + kk + i * 8 * 512, &Bs[nxt][boff + i * 512]);
            asm volatile("s_waitcnt vmcnt(%0)" :: "n"(LOADS) : "memory");
        } else {
            asm volatile("s_waitcnt vmcnt(0)" ::: "memory");
        }
        __builtin_amdgcn_s_barrier();
        asm volatile("" ::: "memory");
#pragma unroll
        for (int ks = 0; ks < 2; ++ks) {
            int blk = ks ? blk1 : blk0;
            bf16x8 av[MW], bv[4];
#pragma unroll
            for (int i = 0; i < MW; ++i)
                av[i] = *(const bf16x8*)&As[cur][(wr * (M / 2) + i * 16 + rl) * 64 + blk];
#pragma unroll
            for (int i = 0; i < 4; ++i)
                bv[i] = *(const bf16x8*)&Bs[cur][(wc * 64 + i * 16 + rl) * 64 + blk];
#pragma unroll
            for (int mt = 0; mt < MW; ++mt)
#pragma unroll
                for (int nt = 0; nt < 4; ++nt)
                    acc[mt][nt] = __builtin_amdgcn_mfma_f32_16x16x32_bf16(
                        av[mt], bv[nt], acc[mt][nt], 0, 0, 0);
        }
        asm volatile("" ::: "memory");
        __builtin_amdgcn_s_barrier();
    }

    int rh = lane >> 4;
#pragma unroll
    for (int mt = 0; mt < MW; ++mt)
#pragma unroll
        for (int nt = 0; nt < 4; ++nt)
#pragma unroll
            for (int rr = 0; rr < 4; ++rr) {
                size_t grow = row0 + wr * (M / 2) + mt * 16 + rh * 4 + rr;
                int c = c0 + wc * 64 + nt * 16 + rl;
                float v = acc[mt][nt][rr];
                if (OP == 0) {
                    // per-64-col-segment st8 swizzle (feeds attn gload staging)
                    ((u16*)Cptr)[grow * N + (c ^ (((int)grow & 7) << 3))] = f2bf(v);
                } else if (OP == 1) {
                    ((float*)Cptr)[grow * 512 + c] += v + Bbase[(size_t)e * bestride + c];
                } else {
                    float vb = v + Bbase[(size_t)e * bestride + c];
                    float gl = vb * 0.5f * (1.f + erff(vb * 0.70710678118f));
                    ((u16*)Cptr)[grow * 512 + (c ^ (((int)grow & 7) << 3))] = f2bf(gl);
                }
            }
}

// ---------------------------------------------------------------------------
// MFMA attention, m97 staging: global_load_lds of seg-swizzled qb16 into
// linear LDS [80][64]/[72][64]; frag reads XOR with ((pr+rl)&7)<<3 (global
// row key). Pad rows >=65 hold garbage — K cols masked in softmax, V zeroed
// in transpose, Q/P/O pad rows never written (row-wise MFMA independence).
// 1-D grid 1024 (b-major), 5 waves, wave = m-tile. Out st8-SWIZZLED.
// ---------------------------------------------------------------------------
#define ATT_LDS (80 * 64 + 80 * 64 + 72 * 64 + 64 * 96)   // u16 elems (41 KB)
__global__ __launch_bounds__(320) void attn4_k(const u16* __restrict__ qkv,
                                               u16* __restrict__ o,
                                               const int* __restrict__ prow) {
    int b = blockIdx.x & 127, h = blockIdx.x >> 7, tid = threadIdx.x;
    int pr = prow[b];
    __shared__ __align__(16) u16 smem[ATT_LDS];
    u16* Qs = smem;                    // [80][64] seg-swizzled
    u16* Ks = smem + 80 * 64;          // [80][64]
    u16* Ps = smem;                    // [80][96] aliases Qs/Ks after barrier
    u16* Vs = smem + 2 * 80 * 64;      // [72][64]
    u16* Vt = Vs + 72 * 64;            // [64][96]

    int lane = tid & 63, w = tid >> 6;   // wave 0..4

    // --- gload staging: Q rows w*16..+16, K same, V rows (w<4: w*16..+16;
    //     w==4: rows 64..72). Over-reads into qb16 slack rows (garbage OK).
    {
        const u16* qg = qkv + (size_t)(pr + w * 16 + (lane >> 3)) * 1536 +
                        h * 64 + (lane & 7) * 8;
        u16* qd = Qs + w * 16 * 64;
        GLOAD_LDS16(qg, qd);
        GLOAD_LDS16(qg + 8 * 1536, qd + 512);
        const u16* kgp = qg + 512;
        u16* kd = Ks + w * 16 * 64;
        GLOAD_LDS16(kgp, kd);
        GLOAD_LDS16(kgp + 8 * 1536, kd + 512);
        if (w < 4) {
            const u16* vg = qg + 1024;
            u16* vd = Vs + w * 16 * 64;
            GLOAD_LDS16(vg, vd);
            GLOAD_LDS16(vg + 8 * 1536, vd + 512);
        } else {
            const u16* vg = qkv + (size_t)(pr + 64 + (lane >> 3)) * 1536 +
                            1024 + h * 64 + (lane & 7) * 8;
            GLOAD_LDS16(vg, Vs + 64 * 64);
        }
    }
    __syncthreads();

    int mt = w;
    int rl = lane & 15, kg = lane >> 4, g = lane >> 4;
    int skey = ((pr + rl) & 7) << 3;          // global-row swizzle key
    int blkA = (kg * 8) ^ skey;
    int blkB = ((4 + kg) * 8) ^ skey;

    f32x4 acc[5];
#pragma unroll
    for (int nt = 0; nt < 5; ++nt) acc[nt] = (f32x4){0.f, 0.f, 0.f, 0.f};

    __builtin_amdgcn_s_setprio(1);
    {
        bf16x8 av0 = *(const bf16x8*)&Qs[(mt * 16 + rl) * 64 + blkA];
        bf16x8 av1 = *(const bf16x8*)&Qs[(mt * 16 + rl) * 64 + blkB];
#pragma unroll
        for (int nt = 0; nt < 5; ++nt) {
            bf16x8 bv0 = *(const bf16x8*)&Ks[(nt * 16 + rl) * 64 + blkA];
            bf16x8 bv1 = *(const bf16x8*)&Ks[(nt * 16 + rl) * 64 + blkB];
            acc[nt] = __builtin_amdgcn_mfma_f32_16x16x32_bf16(av0, bv0, acc[nt], 0, 0, 0);
            acc[nt] = __builtin_amdgcn_mfma_f32_16x16x32_bf16(av1, bv1, acc[nt], 0, 0, 0);
        }
    }
    __builtin_amdgcn_s_setprio(0);

    // Transpose V -> Vt[64][96] (k >= 65 zero; Vs is seg-swizzled)
    for (int idx = tid; idx < 768; idx += 320) {
        int d = idx & 63, kq = idx >> 6;
        u16 tmp[8];
#pragma unroll
        for (int j = 0; j < 8; ++j) {
            int k = kq * 8 + j;
            tmp[j] = (k < NTOK) ? Vs[k * 64 + (d ^ (((pr + k) & 7) << 3))] : (u16)0;
        }
        *(int4*)&Vt[d * 96 + kq * 8] = *(int4*)tmp;
    }

    // Softmax in registers: row = mt*16 + g*4 + r, col = nt*16 + rl
#pragma unroll
    for (int r = 0; r < 4; ++r) {
        float m = -3.0e38f;
#pragma unroll
        for (int nt = 0; nt < 5; ++nt) {
            float s = acc[nt][r] * 0.125f;
            if (nt * 16 + rl >= NTOK) s = -3.0e38f;
            acc[nt][r] = s;
            m = fmaxf(m, s);
        }
        m = fmaxf(m, __shfl_xor(m, 1));
        m = fmaxf(m, __shfl_xor(m, 2));
        m = fmaxf(m, __shfl_xor(m, 4));
        m = fmaxf(m, __shfl_xor(m, 8));
        float sum = 0.f;
#pragma unroll
        for (int nt = 0; nt < 5; ++nt) {
            float p = expf(acc[nt][r] - m);
            acc[nt][r] = p;
            sum += p;
        }
        sum += __shfl_xor(sum, 1);
        sum += __shfl_xor(sum, 2);
        sum += __shfl_xor(sum, 4);
        sum += __shfl_xor(sum, 8);
        float inv = 1.f / sum;
#pragma unroll
        for (int nt = 0; nt < 5; ++nt) acc[nt][r] *= inv;
    }
    __syncthreads();   // Qs/Ks dead; P may now be written

#pragma unroll
    for (int nt = 0; nt < 5; ++nt)
#pragma unroll
        for (int r = 0; r < 4; ++r)
            Ps[(mt * 16 + g * 4 + r) * 96 + nt * 16 + rl] = f2bf(acc[nt][r]);
    for (int idx = tid; idx < 160; idx += 320) {
        int r = idx >> 1, hf = idx & 1;
        *(int4*)&Ps[r * 96 + 80 + hf * 8] = (int4){0, 0, 0, 0};
    }
    __syncthreads();

    __builtin_amdgcn_s_setprio(1);
#pragma unroll
    for (int dt = 0; dt < 4; ++dt) {
        f32x4 oa = {0.f, 0.f, 0.f, 0.f};
#pragma unroll
        for (int s2 = 0; s2 < 3; ++s2) {
            bf16x8 av = *(const bf16x8*)&Ps[(mt * 16 + rl) * 96 + s2 * 32 + kg * 8];
            bf16x8 bv = *(const bf16x8*)&Vt[(dt * 16 + rl) * 96 + s2 * 32 + kg * 8];
            oa = __builtin_amdgcn_mfma_f32_16x16x32_bf16(av, bv, oa, 0, 0, 0);
        }
#pragma unroll
        for (int r = 0; r < 4; ++r) {
            int row = mt * 16 + g * 4 + r;
            if (row < NTOK) {
                int grow = pr + row;
                int c = h * 64 + dt * 16 + rl;
                o[(size_t)grow * DIM + (c ^ ((grow & 7) << 3))] = f2bf(oa[r]);
            }
        }
    }
    __builtin_amdgcn_s_setprio(0);
}

// ---------------------------------------------------------------------------
// Final LN (token 0) + head (fp32)
// ---------------------------------------------------------------------------
__global__ __launch_bounds__(64) void final_k(const float* __restrict__ t,
                                              const float* __restrict__ fg,
                                              const float* __restrict__ fb,
                                              const float* __restrict__ hw,
                                              const float* __restrict__ hb,
                                              const int* __restrict__ top1,
                                              const int* __restrict__ prow,
                                              float* __restrict__ out) {
    int b = blockIdx.x, lane = threadIdx.x;
    int e = top1[b];
    const float* row = t + (size_t)prow[b] * DIM;
    float v[8], s = 0.f, q = 0.f;
#pragma unroll
    for (int ii = 0; ii < 8; ++ii) {
        v[ii] = row[ii * 64 + lane];
        s += v[ii];
        q += v[ii] * v[ii];
    }
    for (int off = 32; off > 0; off >>= 1) {
        s += __shfl_xor(s, off);
        q += __shfl_xor(q, off);
    }
    float mean = s * (1.f / DIM);
    float var = q * (1.f / DIM) - mean * mean;
    float rs = rsqrtf(var + 1e-5f);
    float nv[8];
#pragma unroll
    for (int ii = 0; ii < 8; ++ii) {
        int d = ii * 64 + lane;
        nv[ii] = (v[ii] - mean) * rs * fg[e * DIM + d] + fb[e * DIM + d];
    }
    for (int c = 0; c < NCLS; ++c) {
        float p = 0.f;
#pragma unroll
        for (int ii = 0; ii < 8; ++ii) {
            int d = ii * 64 + lane;
            p = fmaf(nv[ii], hw[(size_t)e * DIM * NCLS + d * NCLS + c], p);
        }
        for (int off = 32; off > 0; off >>= 1) p += __shfl_xor(p, off);
        if (lane == 0) out[b * NCLS + c] = p + hb[e * NCLS + c];
    }
}

// ---------------------------------------------------------------------------
extern "C" void kernel_launch(void* const* d_in, const int* in_sizes, int n_in,
                              void* d_out, int out_size, void* d_ws, size_t ws_size,
                              hipStream_t stream) {
    const float* x       = (const float*)d_in[0];
    const float* gate_w  = (const float*)d_in[1];
    const float* gate_b  = (const float*)d_in[2];
    const float* pln1_g  = (const float*)d_in[3];
    const float* pln1_b  = (const float*)d_in[4];
    const float* patch_w = (const float*)d_in[5];
    const float* patch_b = (const float*)d_in[6];
    const float* pln2_g  = (const float*)d_in[7];
    const float* pln2_b  = (const float*)d_in[8];
    const float* cls_tok = (const float*)d_in[9];
    const float* pos_emb = (const float*)d_in[10];
    const float* aln_g   = (const float*)d_in[11];
    const float* aln_b   = (const float*)d_in[12];
    const float* qkv_w   = (const float*)d_in[13];
    const float* out_w   = (const float*)d_in[14];
    const float* out_b   = (const float*)d_in[15];
    const float* fln_g   = (const float*)d_in[16];
    const float* fln_b   = (const float*)d_in[17];
    const float* ff1_w   = (const float*)d_in[18];
    const float* ff1_b   = (const float*)d_in[19];
    const float* ff2_w   = (const float*)d_in[20];
    const float* ff2_b   = (const float*)d_in[21];
    const float* final_g = (const float*)d_in[22];
    const float* final_b = (const float*)d_in[23];
    const float* head_w  = (const float*)d_in[24];
    const float* head_b  = (const float*)d_in[25];
    float* out = (float*)d_out;

    // Workspace (~260 MB of ~600 MB); qb16 has 16 rows of slack for attn's
    // 8-row-aligned gload over-reads.
    int* top1   = (int*)d_ws;                                // 128
    int* prow   = top1 + 128;                                // 128
    int* tile_e = prow + 128;                                // 40 (pad)
    float* t  = (float*)((char*)d_ws + 4096);                // fp32 [NROWSP][512] linear
    u16* aln  = (u16*)(t + (size_t)NROWSP * DIM);            // bf16 [NROWSP][512] SWZ
    u16* qb16 = aln + (size_t)NROWSP * DIM;                  // bf16 [NROWSP+16][1536] seg-SWZ
    u16* ao16 = qb16 + (size_t)(NROWSP + 16) * 1536;         // bf16 [NROWSP][512] SWZ
    u16* h16  = ao16 + (size_t)NROWSP * DIM;                 // bf16 [NROWSP][512] SWZ
    u16* wq_t = h16 + (size_t)NROWSP * DIM;                  // bf16 [48][1536][512] SWZ
    u16* wo_t = wq_t + (size_t)48 * 1536 * 512;              // bf16 [48][512][512] SWZ
    u16* w1_t = wo_t + (size_t)48 * 512 * 512;
    u16* w2_t = w1_t + (size_t)48 * 512 * 512;

    gate_k<<<BATCH, 256, 0, stream>>>(x, gate_w, gate_b, top1);
    route3_k<<<1, 128, 0, stream>>>(top1, prow, tile_e);
    patch_k<<<dim3(NTOK, BATCH), 256, 0, stream>>>(x, pln1_g, pln1_b, patch_w, patch_b,
                                                   pln2_g, pln2_b, cls_tok, pos_emb,
                                                   top1, prow, t);
    wconv_k<<<dim3(48, 16, 48), 256, 0, stream>>>(qkv_w, wq_t, 1536);
    wconv3_k<<<dim3(16, 16, 144), 256, 0, stream>>>(out_w, ff1_w, ff2_w, wo_t, w1_t, w2_t);

    for (int l = 0; l < DEPTH; ++l) {
        ln2_k<<<NROWSP / 4, 256, 0, stream>>>(t, aln, aln_g + l * DIM, aln_b + l * DIM,
                                              tile_e, DEPTH * DIM);
        mgemm_k<1536, 0, 4><<<(NROWSP / 128) * 12, 256, 0, stream>>>(
            aln, wq_t + (size_t)l * 1536 * 512, nullptr, qb16, tile_e,
            DEPTH * 512 * 1536, 0);
        attn4_k<<<HEADS * BATCH, 320, 0, stream>>>(qb16, ao16, prow);
        mgemm_k<512, 1, 2><<<(NROWSP / 64) * 4, 256, 0, stream>>>(
            ao16, wo_t + (size_t)l * 512 * 512, out_b + l * DIM, t, tile_e,
            DEPTH * 512 * 512, DEPTH * DIM);
        ln2_k<<<NROWSP / 4, 256, 0, stream>>>(t, aln, fln_g + l * DIM, fln_b + l * DIM,
                                              tile_e, DEPTH * DIM);
        mgemm_k<512, 2, 2><<<(NROWSP / 64) * 4, 256, 0, stream>>>(
            aln, w1_t + (size_t)l * 512 * 512, ff1_b + l * DIM, h16, tile_e,
            DEPTH * 512 * 512, DEPTH * DIM);
        mgemm_k<512, 1, 2><<<(NROWSP / 64) * 4, 256, 0, stream>>>(
            h16, w2_t + (size_t)l * 512 * 512, ff2_b + l * DIM, t, tile_e,
            DEPTH * 512 * 512, DEPTH * DIM);
    }
    final_k<<<BATCH, 64, 0, stream>>>(t, final_g, final_b, head_w, head_b, top1, prow, out);
}